// Round 1
// baseline (1005.485 us; speedup 1.0000x reference)
//
#include <hip/hip_runtime.h>
#include <math.h>

#define EPSV 1e-5f

// ---------------- K1: conv1d (pad=1,K=3) + bias -> h_perm [s=t*4+ss][n][b], + BN1 partial stats
__global__ __launch_bounds__(256) void k_conv(const float* __restrict__ x, const float* __restrict__ w,
        const float* __restrict__ cb, float* __restrict__ hp, float* __restrict__ s1g, float* __restrict__ s2g){
  __shared__ float xs[32*321];   // [b][tt(10)][i(32)], b-stride 321 to dodge bank conflicts
  __shared__ float ws[32*97];    // [ss*8+nl][96], row stride 97
  __shared__ float bs[32];
  const int tid = threadIdx.x;
  const int t0 = blockIdx.x * 8;      // 64 t-tiles of 8
  const int n0 = blockIdx.y * 8;      // 16 n-groups of 8
  for (int idx = tid; idx < 32*10*32; idx += 256){
    int bq = idx / 320; int rem = idx - bq*320; int tt = rem >> 5; int i = rem & 31;
    int tg = t0 - 1 + tt;
    float v = 0.f;
    if (tg >= 0 && tg < 512) v = x[(bq*512 + tg)*32 + i];
    xs[bq*321 + tt*32 + i] = v;
  }
  for (int idx = tid; idx < 32*96; idx += 256){
    int row = idx / 96; int within = idx - row*96;
    int ss = row >> 3; int nl = row & 7;
    int c = ss*128 + n0 + nl;
    ws[row*97 + within] = w[c*96 + within];
  }
  if (tid < 32){
    int ss = tid >> 3, nl = tid & 7;
    bs[tid] = cb[ss*128 + n0 + nl];
  }
  __syncthreads();
  const int b = tid & 31;
  const int nl = tid >> 5;
  float acc[4][8];
  #pragma unroll
  for (int ss = 0; ss < 4; ++ss){
    float bv = bs[ss*8 + nl];
    #pragma unroll
    for (int t = 0; t < 8; ++t) acc[ss][t] = bv;
  }
  for (int i = 0; i < 32; ++i){
    #pragma unroll
    for (int k = 0; k < 3; ++k){
      float w0 = ws[(0*8+nl)*97 + i*3 + k];
      float w1 = ws[(1*8+nl)*97 + i*3 + k];
      float w2 = ws[(2*8+nl)*97 + i*3 + k];
      float w3 = ws[(3*8+nl)*97 + i*3 + k];
      #pragma unroll
      for (int t = 0; t < 8; ++t){
        float xv = xs[b*321 + (t+k)*32 + i];
        acc[0][t] += xv*w0; acc[1][t] += xv*w1; acc[2][t] += xv*w2; acc[3][t] += xv*w3;
      }
    }
  }
  #pragma unroll
  for (int ss = 0; ss < 4; ++ss){
    int n = n0 + nl;
    float s1 = 0.f, s2 = 0.f;
    #pragma unroll
    for (int t = 0; t < 8; ++t){
      float v = acc[ss][t];
      int s = (t0 + t)*4 + ss;
      hp[s*4096 + n*32 + b] = v;       // [s][n][b]
      s1 += v; s2 += v*v;
    }
    #pragma unroll
    for (int off = 1; off < 32; off <<= 1){
      s1 += __shfl_xor(s1, off);
      s2 += __shfl_xor(s2, off);
    }
    if (b == 0){
      int c = ss*128 + n;
      atomicAdd(&s1g[c], s1);
      atomicAdd(&s2g[c], s2);
    }
  }
}

// ---------------- K2: finalize BN1 -> a1[c], b1[c]
__global__ void k_bn1(const float* __restrict__ s1g, const float* __restrict__ s2g,
                      const float* __restrict__ g, const float* __restrict__ bb,
                      float* __restrict__ a1, float* __restrict__ b1){
  int c = threadIdx.x;  // 512
  float m = s1g[c] * (1.f/16384.f);
  float v = s2g[c] * (1.f/16384.f) - m*m;
  float sc = g[c] * rsqrtf(v + EPSV);
  a1[c] = sc;
  b1[c] = bb[c] - m*sc;
}

// ---------------- K3: fused BN1-apply + LIF1 + per-step BN2(batch) + LIF2 + TS-mean downsample
// grid 16, block 256 = 32 b (low lanes) x 8 n.  mean over batch via ballot+popcount (spikes are 0/1).
__global__ __launch_bounds__(256) void k_lif(const float* __restrict__ hp,
        const float* __restrict__ a1, const float* __restrict__ b1,
        const float* __restrict__ beta1, const float* __restrict__ g2v, const float* __restrict__ b2v,
        const float* __restrict__ beta2, float* __restrict__ md){
  const int tid = threadIdx.x;
  const int b = tid & 31;
  const int n = blockIdx.x * 8 + (tid >> 5);
  float a1r0 = a1[0*128+n], a1r1 = a1[1*128+n], a1r2 = a1[2*128+n], a1r3 = a1[3*128+n];
  float b1r0 = b1[0*128+n], b1r1 = b1[1*128+n], b1r2 = b1[2*128+n], b1r3 = b1[3*128+n];
  float be1 = fminf(fmaxf(beta1[n], 0.f), 0.99f);
  float be2 = fminf(fmaxf(beta2[n], 0.f), 0.99f);
  float g2 = g2v[n], bb2 = b2v[n];
  float m1 = 0.f, r1 = 0.f, m2 = 0.f, r2 = 0.f;
  const float* base = hp + n*32 + b;   // +s*4096
  float c0 = base[0], c1 = base[4096], c2 = base[2*4096], c3 = base[3*4096];

#define LIF_STEP(CV, A1R, B1R) { \
    float x1 = CV*A1R + B1R; \
    m1 = be1*m1 + x1 - r1; \
    bool sp = (m1 > 1.0f); \
    unsigned long long mk = __ballot(sp); \
    float spk = sp ? 1.f : 0.f; r1 = spk; \
    unsigned hf = (tid & 32) ? (unsigned)(mk >> 32) : (unsigned)mk; \
    float mean = (float)__popc(hf) * 0.03125f; \
    float var = mean - mean*mean; \
    float h2 = (spk - mean) * rsqrtf(var + EPSV) * g2 + bb2; \
    m2 = be2*m2 + h2 - r2; \
    r2 = (m2 > 1.0f) ? 1.f : 0.f; \
    accd += m2; }

  for (int t = 0; t < 512; ++t){
    float n0v = 0.f, n1v = 0.f, n2v = 0.f, n3v = 0.f;
    if (t < 511){
      const float* nb = base + (size_t)(t+1)*16384;
      n0v = nb[0]; n1v = nb[4096]; n2v = nb[2*4096]; n3v = nb[3*4096];
    }
    float accd = 0.f;
    LIF_STEP(c0, a1r0, b1r0)
    LIF_STEP(c1, a1r1, b1r1)
    LIF_STEP(c2, a1r2, b1r2)
    LIF_STEP(c3, a1r3, b1r3)
    md[(b*512 + t)*128 + n] = accd * 0.25f;
    c0 = n0v; c1 = n1v; c2 = n2v; c3 = n3v;
  }
#undef LIF_STEP
}

// ---------------- K4: gi = concat(x, mem_down) @ W_ih^T + b_ih   (M=16384, N=384, K=160)
__global__ __launch_bounds__(256) void k_gemm_gi(const float* __restrict__ x, const float* __restrict__ md,
        const float* __restrict__ wih, const float* __restrict__ bih, float* __restrict__ gi){
  __shared__ float As[16*68];
  __shared__ float Bs[16*68];
  const int tid = threadIdx.x;
  const int lk = tid & 15, lr = tid >> 4;
  const int tn = tid & 15, tm = tid >> 4;
  const int mb = blockIdx.x*64, nb = blockIdx.y*64;
  float acc[4][4] = {};
  for (int kc = 0; kc < 10; ++kc){
    int k0 = kc*16;
    #pragma unroll
    for (int p = 0; p < 4; ++p){
      int m = mb + lr + p*16;
      int k = k0 + lk;
      float v = (k < 32) ? x[m*32 + k] : md[m*128 + (k - 32)];
      As[lk*68 + lr + p*16] = v;
      int j = nb + lr + p*16;
      Bs[lk*68 + lr + p*16] = wih[j*160 + k];
    }
    __syncthreads();
    #pragma unroll
    for (int kk = 0; kk < 16; ++kk){
      float4 a4 = *(float4*)&As[kk*68 + tm*4];
      float4 b4 = *(float4*)&Bs[kk*68 + tn*4];
      float aa[4] = {a4.x, a4.y, a4.z, a4.w};
      float bb[4] = {b4.x, b4.y, b4.z, b4.w};
      #pragma unroll
      for (int i2 = 0; i2 < 4; ++i2)
        #pragma unroll
        for (int j2 = 0; j2 < 4; ++j2) acc[i2][j2] += aa[i2]*bb[j2];
    }
    __syncthreads();
  }
  float4 bi = *(const float4*)&bih[nb + tn*4];
  #pragma unroll
  for (int mi = 0; mi < 4; ++mi){
    int m = mb + tm*4 + mi;
    float4 o;
    o.x = acc[mi][0] + bi.x; o.y = acc[mi][1] + bi.y;
    o.z = acc[mi][2] + bi.z; o.w = acc[mi][3] + bi.w;
    *(float4*)&gi[m*384 + nb + tn*4] = o;
  }
}

// ---------------- K5: GRU recurrence. 32 blocks (1 per batch), 384 threads (1 per gate row).
// W_hh row lives in 128 VGPRs; h broadcast from LDS.
__global__ __launch_bounds__(384) void k_gru(const float* __restrict__ gi, const float* __restrict__ whh,
        const float* __restrict__ bhh, float* __restrict__ gout){
  const int b = blockIdx.x, r = threadIdx.x;
  __shared__ float hs[128];
  __shared__ float rg[128];
  __shared__ float zg[128];
  float4 w4[32];
  #pragma unroll
  for (int q = 0; q < 32; ++q) w4[q] = *(const float4*)&whh[r*128 + q*4];
  float bh = bhh[r];
  if (r < 128) hs[r] = 0.f;
  __syncthreads();
  const float* gib = gi + (size_t)b*512*384;
  for (int t = 0; t < 512; ++t){
    float gh = bh;
    #pragma unroll
    for (int q = 0; q < 32; ++q){
      float4 h4 = *(const float4*)&hs[q*4];
      gh += w4[q].x*h4.x + w4[q].y*h4.y + w4[q].z*h4.z + w4[q].w*h4.w;
    }
    float giv = gib[t*384 + r];
    if (r < 128){
      rg[r] = 1.f/(1.f + expf(-(giv + gh)));
    } else if (r < 256){
      zg[r-128] = 1.f/(1.f + expf(-(giv + gh)));
    }
    __syncthreads();
    if (r >= 256){
      int j = r - 256;
      float nn = tanhf(giv + rg[j]*gh);
      float z = zg[j];
      float hn = (1.f - z)*nn + z*hs[j];
      hs[j] = hn;
      gout[(size_t)(b*512 + t)*128 + j] = hn;
    }
    __syncthreads();
  }
}

// ---------------- K6: Q,K,V = g @ [qw;kw;vw]^T + bias  (M=16384, N=384, K=128)
__global__ __launch_bounds__(256) void k_gemm_qkv(const float* __restrict__ g,
        const float* __restrict__ qw, const float* __restrict__ qb2,
        const float* __restrict__ kw, const float* __restrict__ kb2,
        const float* __restrict__ vw, const float* __restrict__ vb2,
        float* __restrict__ Qb, float* __restrict__ Kb, float* __restrict__ Vb){
  __shared__ float As[16*68];
  __shared__ float Bs[16*68];
  const int tid = threadIdx.x;
  const int lk = tid & 15, lr = tid >> 4;
  const int tn = tid & 15, tm = tid >> 4;
  const int mb = blockIdx.x*64, nb = blockIdx.y*64;
  float acc[4][4] = {};
  for (int kc = 0; kc < 8; ++kc){
    int k0 = kc*16;
    #pragma unroll
    for (int p = 0; p < 4; ++p){
      int m = mb + lr + p*16;
      As[lk*68 + lr + p*16] = g[m*128 + k0 + lk];
      int j = nb + lr + p*16;
      const float* wr = (j < 128) ? &qw[j*128] : (j < 256) ? &kw[(j-128)*128] : &vw[(j-256)*128];
      Bs[lk*68 + lr + p*16] = wr[k0 + lk];
    }
    __syncthreads();
    #pragma unroll
    for (int kk = 0; kk < 16; ++kk){
      float4 a4 = *(float4*)&As[kk*68 + tm*4];
      float4 b4 = *(float4*)&Bs[kk*68 + tn*4];
      float aa[4] = {a4.x, a4.y, a4.z, a4.w};
      float bb[4] = {b4.x, b4.y, b4.z, b4.w};
      #pragma unroll
      for (int i2 = 0; i2 < 4; ++i2)
        #pragma unroll
        for (int j2 = 0; j2 < 4; ++j2) acc[i2][j2] += aa[i2]*bb[j2];
    }
    __syncthreads();
  }
  int j0 = nb + tn*4;
  float* dst; const float* bptr; int col;
  if (j0 < 128){ dst = Qb; bptr = qb2; col = j0; }
  else if (j0 < 256){ dst = Kb; bptr = kb2; col = j0 - 128; }
  else { dst = Vb; bptr = vb2; col = j0 - 256; }
  float4 bi = *(const float4*)&bptr[col];
  #pragma unroll
  for (int mi = 0; mi < 4; ++mi){
    int m = mb + tm*4 + mi;
    float4 o;
    o.x = acc[mi][0] + bi.x; o.y = acc[mi][1] + bi.y;
    o.z = acc[mi][2] + bi.z; o.w = acc[mi][3] + bi.w;
    *(float4*)&dst[m*128 + col] = o;
  }
}

// ---------------- K7: a[b][s] = mean_t sigmoid(scale * Q[b,t,:].K[b,s,:])
__global__ __launch_bounds__(256) void k_attn(const float* __restrict__ Qb, const float* __restrict__ Kb,
        float* __restrict__ av){
  __shared__ float Ks[128*68];   // [k][s] pad 68
  __shared__ float Qs[128*36];   // [k][t] pad 36 (32-t chunks)
  __shared__ float asum[64];
  const int tid = threadIdx.x;
  const int st = blockIdx.x;   // 8 s-tiles of 64
  const int b  = blockIdx.y;   // 32
  const float SC = 0.08838834764831845f; // 128^-0.5
  for (int idx = tid; idx < 64*128; idx += 256){
    int s_l = idx >> 7, k = idx & 127;
    Ks[k*68 + s_l] = Kb[(size_t)(b*512 + st*64 + s_l)*128 + k];
  }
  if (tid < 64) asum[tid] = 0.f;
  __syncthreads();
  const int sl = tid & 15, tl = tid >> 4;
  float ps0 = 0.f, ps1 = 0.f, ps2 = 0.f, ps3 = 0.f;
  for (int tc = 0; tc < 16; ++tc){
    for (int idx = tid; idx < 32*128; idx += 256){
      int t_l = idx >> 7, k = idx & 127;
      Qs[k*36 + t_l] = Qb[(size_t)(b*512 + tc*32 + t_l)*128 + k];
    }
    __syncthreads();
    float a00=0,a01=0,a02=0,a03=0,a10=0,a11=0,a12=0,a13=0;
    #pragma unroll 4
    for (int k = 0; k < 128; ++k){
      float2 q2 = *(float2*)&Qs[k*36 + tl*2];
      float4 k4 = *(float4*)&Ks[k*68 + sl*4];
      a00 += q2.x*k4.x; a01 += q2.x*k4.y; a02 += q2.x*k4.z; a03 += q2.x*k4.w;
      a10 += q2.y*k4.x; a11 += q2.y*k4.y; a12 += q2.y*k4.z; a13 += q2.y*k4.w;
    }
    ps0 += 1.f/(1.f+expf(-a00*SC)) + 1.f/(1.f+expf(-a10*SC));
    ps1 += 1.f/(1.f+expf(-a01*SC)) + 1.f/(1.f+expf(-a11*SC));
    ps2 += 1.f/(1.f+expf(-a02*SC)) + 1.f/(1.f+expf(-a12*SC));
    ps3 += 1.f/(1.f+expf(-a03*SC)) + 1.f/(1.f+expf(-a13*SC));
    __syncthreads();
  }
  atomicAdd(&asum[sl*4+0], ps0);
  atomicAdd(&asum[sl*4+1], ps1);
  atomicAdd(&asum[sl*4+2], ps2);
  atomicAdd(&asum[sl*4+3], ps3);
  __syncthreads();
  if (tid < 64) av[b*512 + st*64 + tid] = asum[tid] * (1.f/512.f);
}

// ---------------- K8: out0[b][c] = sum_s a[b][s] * V[b][s][c]
__global__ __launch_bounds__(128) void k_av(const float* __restrict__ av, const float* __restrict__ Vb,
        float* __restrict__ out0){
  int b = blockIdx.x, c = threadIdx.x;
  float acc = 0.f;
  for (int s = 0; s < 512; ++s) acc += av[b*512 + s] * Vb[(size_t)(b*512 + s)*128 + c];
  out0[b*128 + c] = acc;
}

// ---------------- K9: BN3(batch) + head
__global__ __launch_bounds__(256) void k_final(const float* __restrict__ out0,
        const float* __restrict__ g3, const float* __restrict__ b3,
        const float* __restrict__ hw, const float* __restrict__ hb, float* __restrict__ out){
  __shared__ float on[32*132];
  const int tid = threadIdx.x;
  if (tid < 128){
    int c = tid;
    float s = 0.f;
    for (int bq = 0; bq < 32; ++bq) s += out0[bq*128 + c];
    float m = s * (1.f/32.f);
    float v = 0.f;
    for (int bq = 0; bq < 32; ++bq){ float d = out0[bq*128 + c] - m; v += d*d; }
    v *= (1.f/32.f);
    float sc = g3[c] * rsqrtf(v + EPSV);
    float sh = b3[c] - m*sc;
    for (int bq = 0; bq < 32; ++bq) on[bq*132 + c] = out0[bq*128 + c]*sc + sh;
  }
  __syncthreads();
  for (int o = tid; o < 32*96; o += 256){
    int bq = o / 96, hh = o - bq*96;
    float acc = hb[hh];
    for (int k = 0; k < 128; ++k) acc += on[bq*132 + k] * hw[hh*128 + k];
    out[o] = acc;
  }
}

extern "C" void kernel_launch(void* const* d_in, const int* in_sizes, int n_in,
                              void* d_out, int out_size, void* d_ws, size_t ws_size,
                              hipStream_t stream){
  const float* x      = (const float*)d_in[0];
  const float* conv_w = (const float*)d_in[1];
  const float* conv_b = (const float*)d_in[2];
  const float* bn1_g  = (const float*)d_in[3];
  const float* bn1_b  = (const float*)d_in[4];
  const float* beta1  = (const float*)d_in[5];
  const float* bn2_g  = (const float*)d_in[6];
  const float* bn2_b  = (const float*)d_in[7];
  const float* beta2  = (const float*)d_in[8];
  const float* g_wih  = (const float*)d_in[9];
  const float* g_whh  = (const float*)d_in[10];
  const float* g_bih  = (const float*)d_in[11];
  const float* g_bhh  = (const float*)d_in[12];
  const float* q_w    = (const float*)d_in[13];
  const float* q_b    = (const float*)d_in[14];
  const float* k_w    = (const float*)d_in[15];
  const float* k_b    = (const float*)d_in[16];
  const float* v_w    = (const float*)d_in[17];
  const float* v_b    = (const float*)d_in[18];
  const float* bn3_g  = (const float*)d_in[19];
  const float* bn3_b  = (const float*)d_in[20];
  const float* head_w = (const float*)d_in[21];
  const float* head_b = (const float*)d_in[22];

  char* ws = (char*)d_ws;
  // layout (bytes):
  // [0, 33554432)           h_perm   (2048*128*32 f32)   -> later reused: gi (25.2MB) -> later Q/K/V
  // [33554432, 41943040)    mem_down (32*512*128 f32)
  // [41943040, 50331648)    g        (32*512*128 f32)
  // [50331648, ...)         small: s1g, s2g, a1, b1, a_attn, out0
  float* hp  = (float*)ws;
  float* md  = (float*)(ws + 33554432);
  float* g   = (float*)(ws + 41943040);
  float* s1g = (float*)(ws + 50331648);
  float* s2g = (float*)(ws + 50331648 + 2048);
  float* a1  = (float*)(ws + 50331648 + 4096);
  float* b1  = (float*)(ws + 50331648 + 6144);
  float* av  = (float*)(ws + 50331648 + 8192);
  float* out0= (float*)(ws + 50331648 + 8192 + 65536);
  float* gi  = (float*)ws;                      // reuse (h_perm dead after k_lif)
  float* Qb  = (float*)ws;                      // reuse (gi dead after k_gru)
  float* Kb  = (float*)(ws + 8388608);
  float* Vb  = (float*)(ws + 16777216);

  hipMemsetAsync(ws + 50331648, 0, 4096, stream);  // zero BN1 accumulators

  k_conv<<<dim3(64, 16), 256, 0, stream>>>(x, conv_w, conv_b, hp, s1g, s2g);
  k_bn1<<<1, 512, 0, stream>>>(s1g, s2g, bn1_g, bn1_b, a1, b1);
  k_lif<<<16, 256, 0, stream>>>(hp, a1, b1, beta1, bn2_g, bn2_b, beta2, md);
  k_gemm_gi<<<dim3(256, 6), 256, 0, stream>>>(x, md, g_wih, g_bih, gi);
  k_gru<<<32, 384, 0, stream>>>(gi, g_whh, g_bhh, g);
  k_gemm_qkv<<<dim3(256, 6), 256, 0, stream>>>(g, q_w, q_b, k_w, k_b, v_w, v_b, Qb, Kb, Vb);
  k_attn<<<dim3(8, 32), 256, 0, stream>>>(Qb, Kb, av);
  k_av<<<32, 128, 0, stream>>>(av, Vb, out0);
  k_final<<<1, 256, 0, stream>>>(out0, bn3_g, bn3_b, head_w, head_b, (float*)d_out);
}

// Round 2
// 964.127 us; speedup vs baseline: 1.0429x; 1.0429x over previous
//
#include <hip/hip_runtime.h>
#include <math.h>

#define EPSV 1e-5f

// ---------------- K1: conv1d (pad=1,K=3) + bias -> h_perm [s=t*4+ss][n][b], + BN1 partial stats
__global__ __launch_bounds__(256) void k_conv(const float* __restrict__ x, const float* __restrict__ w,
        const float* __restrict__ cb, float* __restrict__ hp, float* __restrict__ s1g, float* __restrict__ s2g){
  __shared__ float xs[32*321];   // [b][tt(10)][i(32)], b-stride 321 to dodge bank conflicts
  __shared__ float ws[32*97];    // [ss*8+nl][96], row stride 97
  __shared__ float bs[32];
  const int tid = threadIdx.x;
  const int t0 = blockIdx.x * 8;      // 64 t-tiles of 8
  const int n0 = blockIdx.y * 8;      // 16 n-groups of 8
  for (int idx = tid; idx < 32*10*32; idx += 256){
    int bq = idx / 320; int rem = idx - bq*320; int tt = rem >> 5; int i = rem & 31;
    int tg = t0 - 1 + tt;
    float v = 0.f;
    if (tg >= 0 && tg < 512) v = x[(bq*512 + tg)*32 + i];
    xs[bq*321 + tt*32 + i] = v;
  }
  for (int idx = tid; idx < 32*96; idx += 256){
    int row = idx / 96; int within = idx - row*96;
    int ss = row >> 3; int nl = row & 7;
    int c = ss*128 + n0 + nl;
    ws[row*97 + within] = w[c*96 + within];
  }
  if (tid < 32){
    int ss = tid >> 3, nl = tid & 7;
    bs[tid] = cb[ss*128 + n0 + nl];
  }
  __syncthreads();
  const int b = tid & 31;
  const int nl = tid >> 5;
  float acc[4][8];
  #pragma unroll
  for (int ss = 0; ss < 4; ++ss){
    float bv = bs[ss*8 + nl];
    #pragma unroll
    for (int t = 0; t < 8; ++t) acc[ss][t] = bv;
  }
  for (int i = 0; i < 32; ++i){
    #pragma unroll
    for (int k = 0; k < 3; ++k){
      float w0 = ws[(0*8+nl)*97 + i*3 + k];
      float w1 = ws[(1*8+nl)*97 + i*3 + k];
      float w2 = ws[(2*8+nl)*97 + i*3 + k];
      float w3 = ws[(3*8+nl)*97 + i*3 + k];
      #pragma unroll
      for (int t = 0; t < 8; ++t){
        float xv = xs[b*321 + (t+k)*32 + i];
        acc[0][t] += xv*w0; acc[1][t] += xv*w1; acc[2][t] += xv*w2; acc[3][t] += xv*w3;
      }
    }
  }
  #pragma unroll
  for (int ss = 0; ss < 4; ++ss){
    int n = n0 + nl;
    float s1 = 0.f, s2 = 0.f;
    #pragma unroll
    for (int t = 0; t < 8; ++t){
      float v = acc[ss][t];
      int s = (t0 + t)*4 + ss;
      hp[s*4096 + n*32 + b] = v;       // [s][n][b]
      s1 += v; s2 += v*v;
    }
    #pragma unroll
    for (int off = 1; off < 32; off <<= 1){
      s1 += __shfl_xor(s1, off);
      s2 += __shfl_xor(s2, off);
    }
    if (b == 0){
      int c = ss*128 + n;
      atomicAdd(&s1g[c], s1);
      atomicAdd(&s2g[c], s2);
    }
  }
}

// ---------------- K2: finalize BN1 -> a1[c], b1[c]
__global__ void k_bn1(const float* __restrict__ s1g, const float* __restrict__ s2g,
                      const float* __restrict__ g, const float* __restrict__ bb,
                      float* __restrict__ a1, float* __restrict__ b1){
  int c = threadIdx.x;  // 512
  float m = s1g[c] * (1.f/16384.f);
  float v = s2g[c] * (1.f/16384.f) - m*m;
  float sc = g[c] * rsqrtf(v + EPSV);
  a1[c] = sc;
  b1[c] = bb[c] - m*sc;
}

// ---------------- K3: fused BN1-apply + LIF1 + per-step BN2(batch) + LIF2 + TS-mean downsample
__global__ __launch_bounds__(256) void k_lif(const float* __restrict__ hp,
        const float* __restrict__ a1, const float* __restrict__ b1,
        const float* __restrict__ beta1, const float* __restrict__ g2v, const float* __restrict__ b2v,
        const float* __restrict__ beta2, float* __restrict__ md){
  const int tid = threadIdx.x;
  const int b = tid & 31;
  const int n = blockIdx.x * 8 + (tid >> 5);
  float a1r0 = a1[0*128+n], a1r1 = a1[1*128+n], a1r2 = a1[2*128+n], a1r3 = a1[3*128+n];
  float b1r0 = b1[0*128+n], b1r1 = b1[1*128+n], b1r2 = b1[2*128+n], b1r3 = b1[3*128+n];
  float be1 = fminf(fmaxf(beta1[n], 0.f), 0.99f);
  float be2 = fminf(fmaxf(beta2[n], 0.f), 0.99f);
  float g2 = g2v[n], bb2 = b2v[n];
  float m1 = 0.f, r1 = 0.f, m2 = 0.f, r2 = 0.f;
  const float* base = hp + n*32 + b;   // +s*4096
  float c0 = base[0], c1 = base[4096], c2 = base[2*4096], c3 = base[3*4096];

#define LIF_STEP(CV, A1R, B1R) { \
    float x1 = CV*A1R + B1R; \
    m1 = be1*m1 + x1 - r1; \
    bool sp = (m1 > 1.0f); \
    unsigned long long mk = __ballot(sp); \
    float spk = sp ? 1.f : 0.f; r1 = spk; \
    unsigned hf = (tid & 32) ? (unsigned)(mk >> 32) : (unsigned)mk; \
    float mean = (float)__popc(hf) * 0.03125f; \
    float var = mean - mean*mean; \
    float h2 = (spk - mean) * rsqrtf(var + EPSV) * g2 + bb2; \
    m2 = be2*m2 + h2 - r2; \
    r2 = (m2 > 1.0f) ? 1.f : 0.f; \
    accd += m2; }

  for (int t = 0; t < 512; ++t){
    float n0v = 0.f, n1v = 0.f, n2v = 0.f, n3v = 0.f;
    if (t < 511){
      const float* nb = base + (size_t)(t+1)*16384;
      n0v = nb[0]; n1v = nb[4096]; n2v = nb[2*4096]; n3v = nb[3*4096];
    }
    float accd = 0.f;
    LIF_STEP(c0, a1r0, b1r0)
    LIF_STEP(c1, a1r1, b1r1)
    LIF_STEP(c2, a1r2, b1r2)
    LIF_STEP(c3, a1r3, b1r3)
    md[(b*512 + t)*128 + n] = accd * 0.25f;
    c0 = n0v; c1 = n1v; c2 = n2v; c3 = n3v;
  }
#undef LIF_STEP
}

// ---------------- K4: gi = concat(x, mem_down) @ W_ih^T + b_ih   (M=16384, N=384, K=160)
__global__ __launch_bounds__(256) void k_gemm_gi(const float* __restrict__ x, const float* __restrict__ md,
        const float* __restrict__ wih, const float* __restrict__ bih, float* __restrict__ gi){
  __shared__ float As[16*68];
  __shared__ float Bs[16*68];
  const int tid = threadIdx.x;
  const int lk = tid & 15, lr = tid >> 4;
  const int tn = tid & 15, tm = tid >> 4;
  const int mb = blockIdx.x*64, nb = blockIdx.y*64;
  float acc[4][4] = {};
  for (int kc = 0; kc < 10; ++kc){
    int k0 = kc*16;
    #pragma unroll
    for (int p = 0; p < 4; ++p){
      int m = mb + lr + p*16;
      int k = k0 + lk;
      float v = (k < 32) ? x[m*32 + k] : md[m*128 + (k - 32)];
      As[lk*68 + lr + p*16] = v;
      int j = nb + lr + p*16;
      Bs[lk*68 + lr + p*16] = wih[j*160 + k];
    }
    __syncthreads();
    #pragma unroll
    for (int kk = 0; kk < 16; ++kk){
      float4 a4 = *(float4*)&As[kk*68 + tm*4];
      float4 b4 = *(float4*)&Bs[kk*68 + tn*4];
      float aa[4] = {a4.x, a4.y, a4.z, a4.w};
      float bb[4] = {b4.x, b4.y, b4.z, b4.w};
      #pragma unroll
      for (int i2 = 0; i2 < 4; ++i2)
        #pragma unroll
        for (int j2 = 0; j2 < 4; ++j2) acc[i2][j2] += aa[i2]*bb[j2];
    }
    __syncthreads();
  }
  float4 bi = *(const float4*)&bih[nb + tn*4];
  #pragma unroll
  for (int mi = 0; mi < 4; ++mi){
    int m = mb + tm*4 + mi;
    float4 o;
    o.x = acc[mi][0] + bi.x; o.y = acc[mi][1] + bi.y;
    o.z = acc[mi][2] + bi.z; o.w = acc[mi][3] + bi.w;
    *(float4*)&gi[m*384 + nb + tn*4] = o;
  }
}

// ---------------- K5: GRU recurrence v2.
// 32 blocks (1/batch), 256 threads = 4 waves. Thread (j = tid>>1, half = tid&1):
// computes all 3 gate dots for output j over K-half [half*64, half*64+64), weights in 192 VGPRs.
// Halves combined with one __shfl_xor per gate. Double-buffered h -> ONE barrier/step.
// gi for t+1 prefetched before the dot product.
__global__ __launch_bounds__(256, 1) void k_gru(const float* __restrict__ gi, const float* __restrict__ whh,
        const float* __restrict__ bhh, float* __restrict__ gout){
  const int b = blockIdx.x;
  const int tid = threadIdx.x;
  const int j = tid >> 1;
  const int half = tid & 1;
  const int k0 = half * 64;
  __shared__ float hs[2][128];
  float4 wr[16], wz[16], wn[16];
  #pragma unroll
  for (int q = 0; q < 16; ++q){
    wr[q] = *(const float4*)&whh[(size_t)(      j)*128 + k0 + q*4];
    wz[q] = *(const float4*)&whh[(size_t)(128 + j)*128 + k0 + q*4];
    wn[q] = *(const float4*)&whh[(size_t)(256 + j)*128 + k0 + q*4];
  }
  float bh_r = 0.f, bh_z = 0.f, bh_n = 0.f;
  float gir = 0.f, giz = 0.f, gin = 0.f;
  const float* gib = gi + (size_t)b*512*384;
  if (!half){
    bh_r = bhh[j]; bh_z = bhh[128+j]; bh_n = bhh[256+j];
    gir = gib[j]; giz = gib[128+j]; gin = gib[256+j];   // prefetch t=0
  }
  if (tid < 128) hs[0][tid] = 0.f;
  float hprev = 0.f;
  __syncthreads();
  for (int t = 0; t < 512; ++t){
    // prefetch gi for t+1 (hides HBM/L3 latency under the dot product)
    float ngir = 0.f, ngiz = 0.f, ngin = 0.f;
    if (!half && t < 511){
      const float* gp = gib + (size_t)(t+1)*384;
      ngir = gp[j]; ngiz = gp[128+j]; ngin = gp[256+j];
    }
    const float* hr = hs[t & 1];
    float ar = 0.f, az = 0.f, an = 0.f;
    #pragma unroll
    for (int q = 0; q < 16; ++q){
      float4 h4 = *(const float4*)&hr[k0 + q*4];
      ar += wr[q].x*h4.x + wr[q].y*h4.y + wr[q].z*h4.z + wr[q].w*h4.w;
      az += wz[q].x*h4.x + wz[q].y*h4.y + wz[q].z*h4.z + wz[q].w*h4.w;
      an += wn[q].x*h4.x + wn[q].y*h4.y + wn[q].z*h4.z + wn[q].w*h4.w;
    }
    ar += __shfl_xor(ar, 1);
    az += __shfl_xor(az, 1);
    an += __shfl_xor(an, 1);
    if (!half){
      float r = 1.f/(1.f + expf(-(gir + ar + bh_r)));
      float z = 1.f/(1.f + expf(-(giz + az + bh_z)));
      float nn = tanhf(gin + r*(an + bh_n));
      float hn = (1.f - z)*nn + z*hprev;
      hprev = hn;
      hs[(t + 1) & 1][j] = hn;
      gout[((size_t)b*512 + t)*128 + j] = hn;
    }
    gir = ngir; giz = ngiz; gin = ngin;
    __syncthreads();
  }
}

// ---------------- K6: Q,K,V = g @ [qw;kw;vw]^T + bias  (M=16384, N=384, K=128)
__global__ __launch_bounds__(256) void k_gemm_qkv(const float* __restrict__ g,
        const float* __restrict__ qw, const float* __restrict__ qb2,
        const float* __restrict__ kw, const float* __restrict__ kb2,
        const float* __restrict__ vw, const float* __restrict__ vb2,
        float* __restrict__ Qb, float* __restrict__ Kb, float* __restrict__ Vb){
  __shared__ float As[16*68];
  __shared__ float Bs[16*68];
  const int tid = threadIdx.x;
  const int lk = tid & 15, lr = tid >> 4;
  const int tn = tid & 15, tm = tid >> 4;
  const int mb = blockIdx.x*64, nb = blockIdx.y*64;
  float acc[4][4] = {};
  for (int kc = 0; kc < 8; ++kc){
    int k0 = kc*16;
    #pragma unroll
    for (int p = 0; p < 4; ++p){
      int m = mb + lr + p*16;
      As[lk*68 + lr + p*16] = g[m*128 + k0 + lk];
      int j = nb + lr + p*16;
      const float* wr = (j < 128) ? &qw[j*128] : (j < 256) ? &kw[(j-128)*128] : &vw[(j-256)*128];
      Bs[lk*68 + lr + p*16] = wr[k0 + lk];
    }
    __syncthreads();
    #pragma unroll
    for (int kk = 0; kk < 16; ++kk){
      float4 a4 = *(float4*)&As[kk*68 + tm*4];
      float4 b4 = *(float4*)&Bs[kk*68 + tn*4];
      float aa[4] = {a4.x, a4.y, a4.z, a4.w};
      float bb[4] = {b4.x, b4.y, b4.z, b4.w};
      #pragma unroll
      for (int i2 = 0; i2 < 4; ++i2)
        #pragma unroll
        for (int j2 = 0; j2 < 4; ++j2) acc[i2][j2] += aa[i2]*bb[j2];
    }
    __syncthreads();
  }
  int j0 = nb + tn*4;
  float* dst; const float* bptr; int col;
  if (j0 < 128){ dst = Qb; bptr = qb2; col = j0; }
  else if (j0 < 256){ dst = Kb; bptr = kb2; col = j0 - 128; }
  else { dst = Vb; bptr = vb2; col = j0 - 256; }
  float4 bi = *(const float4*)&bptr[col];
  #pragma unroll
  for (int mi = 0; mi < 4; ++mi){
    int m = mb + tm*4 + mi;
    float4 o;
    o.x = acc[mi][0] + bi.x; o.y = acc[mi][1] + bi.y;
    o.z = acc[mi][2] + bi.z; o.w = acc[mi][3] + bi.w;
    *(float4*)&dst[m*128 + col] = o;
  }
}

// ---------------- K7: a[b][s] = mean_t sigmoid(scale * Q[b,t,:].K[b,s,:])
__global__ __launch_bounds__(256) void k_attn(const float* __restrict__ Qb, const float* __restrict__ Kb,
        float* __restrict__ av){
  __shared__ float Ks[128*68];   // [k][s] pad 68
  __shared__ float Qs[128*36];   // [k][t] pad 36 (32-t chunks)
  __shared__ float asum[64];
  const int tid = threadIdx.x;
  const int st = blockIdx.x;   // 8 s-tiles of 64
  const int b  = blockIdx.y;   // 32
  const float SC = 0.08838834764831845f; // 128^-0.5
  for (int idx = tid; idx < 64*128; idx += 256){
    int s_l = idx >> 7, k = idx & 127;
    Ks[k*68 + s_l] = Kb[(size_t)(b*512 + st*64 + s_l)*128 + k];
  }
  if (tid < 64) asum[tid] = 0.f;
  __syncthreads();
  const int sl = tid & 15, tl = tid >> 4;
  float ps0 = 0.f, ps1 = 0.f, ps2 = 0.f, ps3 = 0.f;
  for (int tc = 0; tc < 16; ++tc){
    for (int idx = tid; idx < 32*128; idx += 256){
      int t_l = idx >> 7, k = idx & 127;
      Qs[k*36 + t_l] = Qb[(size_t)(b*512 + tc*32 + t_l)*128 + k];
    }
    __syncthreads();
    float a00=0,a01=0,a02=0,a03=0,a10=0,a11=0,a12=0,a13=0;
    #pragma unroll 4
    for (int k = 0; k < 128; ++k){
      float2 q2 = *(float2*)&Qs[k*36 + tl*2];
      float4 k4 = *(float4*)&Ks[k*68 + sl*4];
      a00 += q2.x*k4.x; a01 += q2.x*k4.y; a02 += q2.x*k4.z; a03 += q2.x*k4.w;
      a10 += q2.y*k4.x; a11 += q2.y*k4.y; a12 += q2.y*k4.z; a13 += q2.y*k4.w;
    }
    ps0 += 1.f/(1.f+expf(-a00*SC)) + 1.f/(1.f+expf(-a10*SC));
    ps1 += 1.f/(1.f+expf(-a01*SC)) + 1.f/(1.f+expf(-a11*SC));
    ps2 += 1.f/(1.f+expf(-a02*SC)) + 1.f/(1.f+expf(-a12*SC));
    ps3 += 1.f/(1.f+expf(-a03*SC)) + 1.f/(1.f+expf(-a13*SC));
    __syncthreads();
  }
  atomicAdd(&asum[sl*4+0], ps0);
  atomicAdd(&asum[sl*4+1], ps1);
  atomicAdd(&asum[sl*4+2], ps2);
  atomicAdd(&asum[sl*4+3], ps3);
  __syncthreads();
  if (tid < 64) av[b*512 + st*64 + tid] = asum[tid] * (1.f/512.f);
}

// ---------------- K8: out0[b][c] = sum_s a[b][s] * V[b][s][c]
__global__ __launch_bounds__(128) void k_av(const float* __restrict__ av, const float* __restrict__ Vb,
        float* __restrict__ out0){
  int b = blockIdx.x, c = threadIdx.x;
  float acc = 0.f;
  for (int s = 0; s < 512; ++s) acc += av[b*512 + s] * Vb[(size_t)(b*512 + s)*128 + c];
  out0[b*128 + c] = acc;
}

// ---------------- K9: BN3(batch) + head
__global__ __launch_bounds__(256) void k_final(const float* __restrict__ out0,
        const float* __restrict__ g3, const float* __restrict__ b3,
        const float* __restrict__ hw, const float* __restrict__ hb, float* __restrict__ out){
  __shared__ float on[32*132];
  const int tid = threadIdx.x;
  if (tid < 128){
    int c = tid;
    float s = 0.f;
    for (int bq = 0; bq < 32; ++bq) s += out0[bq*128 + c];
    float m = s * (1.f/32.f);
    float v = 0.f;
    for (int bq = 0; bq < 32; ++bq){ float d = out0[bq*128 + c] - m; v += d*d; }
    v *= (1.f/32.f);
    float sc = g3[c] * rsqrtf(v + EPSV);
    float sh = b3[c] - m*sc;
    for (int bq = 0; bq < 32; ++bq) on[bq*132 + c] = out0[bq*128 + c]*sc + sh;
  }
  __syncthreads();
  for (int o = tid; o < 32*96; o += 256){
    int bq = o / 96, hh = o - bq*96;
    float acc = hb[hh];
    for (int k = 0; k < 128; ++k) acc += on[bq*132 + k] * hw[hh*128 + k];
    out[o] = acc;
  }
}

extern "C" void kernel_launch(void* const* d_in, const int* in_sizes, int n_in,
                              void* d_out, int out_size, void* d_ws, size_t ws_size,
                              hipStream_t stream){
  const float* x      = (const float*)d_in[0];
  const float* conv_w = (const float*)d_in[1];
  const float* conv_b = (const float*)d_in[2];
  const float* bn1_g  = (const float*)d_in[3];
  const float* bn1_b  = (const float*)d_in[4];
  const float* beta1  = (const float*)d_in[5];
  const float* bn2_g  = (const float*)d_in[6];
  const float* bn2_b  = (const float*)d_in[7];
  const float* beta2  = (const float*)d_in[8];
  const float* g_wih  = (const float*)d_in[9];
  const float* g_whh  = (const float*)d_in[10];
  const float* g_bih  = (const float*)d_in[11];
  const float* g_bhh  = (const float*)d_in[12];
  const float* q_w    = (const float*)d_in[13];
  const float* q_b    = (const float*)d_in[14];
  const float* k_w    = (const float*)d_in[15];
  const float* k_b    = (const float*)d_in[16];
  const float* v_w    = (const float*)d_in[17];
  const float* v_b    = (const float*)d_in[18];
  const float* bn3_g  = (const float*)d_in[19];
  const float* bn3_b  = (const float*)d_in[20];
  const float* head_w = (const float*)d_in[21];
  const float* head_b = (const float*)d_in[22];

  char* ws = (char*)d_ws;
  float* hp  = (float*)ws;
  float* md  = (float*)(ws + 33554432);
  float* g   = (float*)(ws + 41943040);
  float* s1g = (float*)(ws + 50331648);
  float* s2g = (float*)(ws + 50331648 + 2048);
  float* a1  = (float*)(ws + 50331648 + 4096);
  float* b1  = (float*)(ws + 50331648 + 6144);
  float* av  = (float*)(ws + 50331648 + 8192);
  float* out0= (float*)(ws + 50331648 + 8192 + 65536);
  float* gi  = (float*)ws;                      // reuse (h_perm dead after k_lif)
  float* Qb  = (float*)ws;                      // reuse (gi dead after k_gru)
  float* Kb  = (float*)(ws + 8388608);
  float* Vb  = (float*)(ws + 16777216);

  hipMemsetAsync(ws + 50331648, 0, 4096, stream);  // zero BN1 accumulators

  k_conv<<<dim3(64, 16), 256, 0, stream>>>(x, conv_w, conv_b, hp, s1g, s2g);
  k_bn1<<<1, 512, 0, stream>>>(s1g, s2g, bn1_g, bn1_b, a1, b1);
  k_lif<<<16, 256, 0, stream>>>(hp, a1, b1, beta1, bn2_g, bn2_b, beta2, md);
  k_gemm_gi<<<dim3(256, 6), 256, 0, stream>>>(x, md, g_wih, g_bih, gi);
  k_gru<<<32, 256, 0, stream>>>(gi, g_whh, g_bhh, g);
  k_gemm_qkv<<<dim3(256, 6), 256, 0, stream>>>(g, q_w, q_b, k_w, k_b, v_w, v_b, Qb, Kb, Vb);
  k_attn<<<dim3(8, 32), 256, 0, stream>>>(Qb, Kb, av);
  k_av<<<32, 128, 0, stream>>>(av, Vb, out0);
  k_final<<<1, 256, 0, stream>>>(out0, bn3_g, bn3_b, head_w, head_b, (float*)d_out);
}

// Round 3
// 903.574 us; speedup vs baseline: 1.1128x; 1.0670x over previous
//
#include <hip/hip_runtime.h>
#include <math.h>

#define EPSV 1e-5f

#if __has_builtin(__builtin_amdgcn_exp2f)
#define EXP2F(x) __builtin_amdgcn_exp2f(x)
#else
#define EXP2F(x) exp2f(x)
#endif
#if __has_builtin(__builtin_amdgcn_rcpf)
#define RCPF(x) __builtin_amdgcn_rcpf(x)
#else
#define RCPF(x) (1.0f/(x))
#endif

__device__ __forceinline__ float fsigmoid(float x){
  // 1/(1+2^(-x*log2e))  -- v_exp_f32 + v_rcp_f32, no libcalls
  return RCPF(1.0f + EXP2F(-1.4426950408889634f * x));
}
__device__ __forceinline__ float ftanh(float x){
  // tanh(x) = 1/(0.5 + 0.5*2^(-2x*log2e)) - 1
  return RCPF(0.5f + 0.5f * EXP2F(-2.8853900817779268f * x)) - 1.0f;
}

// ---------------- K1: conv1d (pad=1,K=3) + bias -> h_perm [s=t*4+ss][n][b], + BN1 partial stats
__global__ __launch_bounds__(256) void k_conv(const float* __restrict__ x, const float* __restrict__ w,
        const float* __restrict__ cb, float* __restrict__ hp, float* __restrict__ s1g, float* __restrict__ s2g){
  __shared__ float xs[32*321];   // [b][tt(10)][i(32)], b-stride 321 to dodge bank conflicts
  __shared__ float ws[32*97];    // [ss*8+nl][96], row stride 97
  __shared__ float bs[32];
  const int tid = threadIdx.x;
  const int t0 = blockIdx.x * 8;      // 64 t-tiles of 8
  const int n0 = blockIdx.y * 8;      // 16 n-groups of 8
  for (int idx = tid; idx < 32*10*32; idx += 256){
    int bq = idx / 320; int rem = idx - bq*320; int tt = rem >> 5; int i = rem & 31;
    int tg = t0 - 1 + tt;
    float v = 0.f;
    if (tg >= 0 && tg < 512) v = x[(bq*512 + tg)*32 + i];
    xs[bq*321 + tt*32 + i] = v;
  }
  for (int idx = tid; idx < 32*96; idx += 256){
    int row = idx / 96; int within = idx - row*96;
    int ss = row >> 3; int nl = row & 7;
    int c = ss*128 + n0 + nl;
    ws[row*97 + within] = w[c*96 + within];
  }
  if (tid < 32){
    int ss = tid >> 3, nl = tid & 7;
    bs[tid] = cb[ss*128 + n0 + nl];
  }
  __syncthreads();
  const int b = tid & 31;
  const int nl = tid >> 5;
  float acc[4][8];
  #pragma unroll
  for (int ss = 0; ss < 4; ++ss){
    float bv = bs[ss*8 + nl];
    #pragma unroll
    for (int t = 0; t < 8; ++t) acc[ss][t] = bv;
  }
  for (int i = 0; i < 32; ++i){
    #pragma unroll
    for (int k = 0; k < 3; ++k){
      float w0 = ws[(0*8+nl)*97 + i*3 + k];
      float w1 = ws[(1*8+nl)*97 + i*3 + k];
      float w2 = ws[(2*8+nl)*97 + i*3 + k];
      float w3 = ws[(3*8+nl)*97 + i*3 + k];
      #pragma unroll
      for (int t = 0; t < 8; ++t){
        float xv = xs[b*321 + (t+k)*32 + i];
        acc[0][t] += xv*w0; acc[1][t] += xv*w1; acc[2][t] += xv*w2; acc[3][t] += xv*w3;
      }
    }
  }
  #pragma unroll
  for (int ss = 0; ss < 4; ++ss){
    int n = n0 + nl;
    float s1 = 0.f, s2 = 0.f;
    #pragma unroll
    for (int t = 0; t < 8; ++t){
      float v = acc[ss][t];
      int s = (t0 + t)*4 + ss;
      hp[s*4096 + n*32 + b] = v;       // [s][n][b]
      s1 += v; s2 += v*v;
    }
    #pragma unroll
    for (int off = 1; off < 32; off <<= 1){
      s1 += __shfl_xor(s1, off);
      s2 += __shfl_xor(s2, off);
    }
    if (b == 0){
      int c = ss*128 + n;
      atomicAdd(&s1g[c], s1);
      atomicAdd(&s2g[c], s2);
    }
  }
}

// ---------------- K2: finalize BN1 -> a1[c], b1[c]
__global__ void k_bn1(const float* __restrict__ s1g, const float* __restrict__ s2g,
                      const float* __restrict__ g, const float* __restrict__ bb,
                      float* __restrict__ a1, float* __restrict__ b1){
  int c = threadIdx.x;  // 512
  float m = s1g[c] * (1.f/16384.f);
  float v = s2g[c] * (1.f/16384.f) - m*m;
  float sc = g[c] * rsqrtf(v + EPSV);
  a1[c] = sc;
  b1[c] = bb[c] - m*sc;
}

// ---------------- K3: fused BN1-apply + LIF1 + per-step BN2(batch) + LIF2 + TS-mean downsample
__global__ __launch_bounds__(256) void k_lif(const float* __restrict__ hp,
        const float* __restrict__ a1, const float* __restrict__ b1,
        const float* __restrict__ beta1, const float* __restrict__ g2v, const float* __restrict__ b2v,
        const float* __restrict__ beta2, float* __restrict__ md){
  const int tid = threadIdx.x;
  const int b = tid & 31;
  const int n = blockIdx.x * 8 + (tid >> 5);
  float a1r0 = a1[0*128+n], a1r1 = a1[1*128+n], a1r2 = a1[2*128+n], a1r3 = a1[3*128+n];
  float b1r0 = b1[0*128+n], b1r1 = b1[1*128+n], b1r2 = b1[2*128+n], b1r3 = b1[3*128+n];
  float be1 = fminf(fmaxf(beta1[n], 0.f), 0.99f);
  float be2 = fminf(fmaxf(beta2[n], 0.f), 0.99f);
  float g2 = g2v[n], bb2 = b2v[n];
  float m1 = 0.f, r1 = 0.f, m2 = 0.f, r2 = 0.f;
  const float* base = hp + n*32 + b;   // +s*4096
  float c0 = base[0], c1 = base[4096], c2 = base[2*4096], c3 = base[3*4096];

#define LIF_STEP(CV, A1R, B1R) { \
    float x1 = CV*A1R + B1R; \
    m1 = be1*m1 + x1 - r1; \
    bool sp = (m1 > 1.0f); \
    unsigned long long mk = __ballot(sp); \
    float spk = sp ? 1.f : 0.f; r1 = spk; \
    unsigned hf = (tid & 32) ? (unsigned)(mk >> 32) : (unsigned)mk; \
    float mean = (float)__popc(hf) * 0.03125f; \
    float var = mean - mean*mean; \
    float h2 = (spk - mean) * rsqrtf(var + EPSV) * g2 + bb2; \
    m2 = be2*m2 + h2 - r2; \
    r2 = (m2 > 1.0f) ? 1.f : 0.f; \
    accd += m2; }

  for (int t = 0; t < 512; ++t){
    float n0v = 0.f, n1v = 0.f, n2v = 0.f, n3v = 0.f;
    if (t < 511){
      const float* nb = base + (size_t)(t+1)*16384;
      n0v = nb[0]; n1v = nb[4096]; n2v = nb[2*4096]; n3v = nb[3*4096];
    }
    float accd = 0.f;
    LIF_STEP(c0, a1r0, b1r0)
    LIF_STEP(c1, a1r1, b1r1)
    LIF_STEP(c2, a1r2, b1r2)
    LIF_STEP(c3, a1r3, b1r3)
    md[(b*512 + t)*128 + n] = accd * 0.25f;
    c0 = n0v; c1 = n1v; c2 = n2v; c3 = n3v;
  }
#undef LIF_STEP
}

// ---------------- K4: gi = concat(x, mem_down) @ W_ih^T + b_ih   (M=16384, N=384, K=160)
__global__ __launch_bounds__(256) void k_gemm_gi(const float* __restrict__ x, const float* __restrict__ md,
        const float* __restrict__ wih, const float* __restrict__ bih, float* __restrict__ gi){
  __shared__ float As[16*68];
  __shared__ float Bs[16*68];
  const int tid = threadIdx.x;
  const int lk = tid & 15, lr = tid >> 4;
  const int tn = tid & 15, tm = tid >> 4;
  const int mb = blockIdx.x*64, nb = blockIdx.y*64;
  float acc[4][4] = {};
  for (int kc = 0; kc < 10; ++kc){
    int k0 = kc*16;
    #pragma unroll
    for (int p = 0; p < 4; ++p){
      int m = mb + lr + p*16;
      int k = k0 + lk;
      float v = (k < 32) ? x[m*32 + k] : md[m*128 + (k - 32)];
      As[lk*68 + lr + p*16] = v;
      int j = nb + lr + p*16;
      Bs[lk*68 + lr + p*16] = wih[j*160 + k];
    }
    __syncthreads();
    #pragma unroll
    for (int kk = 0; kk < 16; ++kk){
      float4 a4 = *(float4*)&As[kk*68 + tm*4];
      float4 b4 = *(float4*)&Bs[kk*68 + tn*4];
      float aa[4] = {a4.x, a4.y, a4.z, a4.w};
      float bb[4] = {b4.x, b4.y, b4.z, b4.w};
      #pragma unroll
      for (int i2 = 0; i2 < 4; ++i2)
        #pragma unroll
        for (int j2 = 0; j2 < 4; ++j2) acc[i2][j2] += aa[i2]*bb[j2];
    }
    __syncthreads();
  }
  float4 bi = *(const float4*)&bih[nb + tn*4];
  #pragma unroll
  for (int mi = 0; mi < 4; ++mi){
    int m = mb + tm*4 + mi;
    float4 o;
    o.x = acc[mi][0] + bi.x; o.y = acc[mi][1] + bi.y;
    o.z = acc[mi][2] + bi.z; o.w = acc[mi][3] + bi.w;
    *(float4*)&gi[m*384 + nb + tn*4] = o;
  }
}

// ---------------- K5: GRU recurrence v3.
// 32 blocks (1/batch), 256 threads = 4 waves. Thread (j = tid>>1, half = tid&1):
// all 3 gate dots for output j over K-half, weights in 192 VGPRs (NO libcalls -> RA can use them).
// One barrier/step via double-buffered h; gi prefetched one step ahead.
__global__ __launch_bounds__(256, 1) void k_gru(const float* __restrict__ gi, const float* __restrict__ whh,
        const float* __restrict__ bhh, float* __restrict__ gout){
  const int b = blockIdx.x;
  const int tid = threadIdx.x;
  const int j = tid >> 1;
  const int half = tid & 1;
  const int k0 = half * 64;
  __shared__ float hs[2][2][68];   // [buf][half][64 +4 pad] -> halves on disjoint banks
  float4 wr[16], wz[16], wn[16];
  #pragma unroll
  for (int q = 0; q < 16; ++q){
    wr[q] = *(const float4*)&whh[(size_t)(      j)*128 + k0 + q*4];
    wz[q] = *(const float4*)&whh[(size_t)(128 + j)*128 + k0 + q*4];
    wn[q] = *(const float4*)&whh[(size_t)(256 + j)*128 + k0 + q*4];
  }
  float bh_r = 0.f, bh_z = 0.f, bh_n = 0.f;
  float gir = 0.f, giz = 0.f, gin = 0.f;
  const float* gib = gi + (size_t)b*512*384;
  if (!half){
    bh_r = bhh[j]; bh_z = bhh[128+j]; bh_n = bhh[256+j];
    gir = gib[j]; giz = gib[128+j]; gin = gib[256+j];   // prefetch t=0
  }
  if (tid < 128){ hs[0][tid >> 6][tid & 63] = 0.f; }
  float hprev = 0.f;
  __syncthreads();
  for (int t = 0; t < 512; ++t){
    // prefetch gi for t+1 (hides HBM/L3 latency under the dot product)
    float ngir = 0.f, ngiz = 0.f, ngin = 0.f;
    if (!half && t < 511){
      const float* gp = gib + (size_t)(t+1)*384;
      ngir = gp[j]; ngiz = gp[128+j]; ngin = gp[256+j];
    }
    const float* hr = &hs[t & 1][half][0];
    float ar = 0.f, az = 0.f, an = 0.f;
    #pragma unroll
    for (int q = 0; q < 16; ++q){
      float4 h4 = *(const float4*)&hr[q*4];
      ar += wr[q].x*h4.x + wr[q].y*h4.y + wr[q].z*h4.z + wr[q].w*h4.w;
      az += wz[q].x*h4.x + wz[q].y*h4.y + wz[q].z*h4.z + wz[q].w*h4.w;
      an += wn[q].x*h4.x + wn[q].y*h4.y + wn[q].z*h4.z + wn[q].w*h4.w;
    }
    ar += __shfl_xor(ar, 1);
    az += __shfl_xor(az, 1);
    an += __shfl_xor(an, 1);
    if (!half){
      float r = fsigmoid(gir + ar + bh_r);
      float z = fsigmoid(giz + az + bh_z);
      float nn = ftanh(gin + r*(an + bh_n));
      float hn = (1.f - z)*nn + z*hprev;
      hprev = hn;
      hs[(t + 1) & 1][j >> 6][j & 63] = hn;
      gout[((size_t)b*512 + t)*128 + j] = hn;
    }
    gir = ngir; giz = ngiz; gin = ngin;
    __syncthreads();
  }
}

// ---------------- K6: Q,K,V = g @ [qw;kw;vw]^T + bias  (M=16384, N=384, K=128)
__global__ __launch_bounds__(256) void k_gemm_qkv(const float* __restrict__ g,
        const float* __restrict__ qw, const float* __restrict__ qb2,
        const float* __restrict__ kw, const float* __restrict__ kb2,
        const float* __restrict__ vw, const float* __restrict__ vb2,
        float* __restrict__ Qb, float* __restrict__ Kb, float* __restrict__ Vb){
  __shared__ float As[16*68];
  __shared__ float Bs[16*68];
  const int tid = threadIdx.x;
  const int lk = tid & 15, lr = tid >> 4;
  const int tn = tid & 15, tm = tid >> 4;
  const int mb = blockIdx.x*64, nb = blockIdx.y*64;
  float acc[4][4] = {};
  for (int kc = 0; kc < 8; ++kc){
    int k0 = kc*16;
    #pragma unroll
    for (int p = 0; p < 4; ++p){
      int m = mb + lr + p*16;
      As[lk*68 + lr + p*16] = g[m*128 + k0 + lk];
      int j = nb + lr + p*16;
      const float* wr = (j < 128) ? &qw[j*128] : (j < 256) ? &kw[(j-128)*128] : &vw[(j-256)*128];
      Bs[lk*68 + lr + p*16] = wr[k0 + lk];
    }
    __syncthreads();
    #pragma unroll
    for (int kk = 0; kk < 16; ++kk){
      float4 a4 = *(float4*)&As[kk*68 + tm*4];
      float4 b4 = *(float4*)&Bs[kk*68 + tn*4];
      float aa[4] = {a4.x, a4.y, a4.z, a4.w};
      float bb[4] = {b4.x, b4.y, b4.z, b4.w};
      #pragma unroll
      for (int i2 = 0; i2 < 4; ++i2)
        #pragma unroll
        for (int j2 = 0; j2 < 4; ++j2) acc[i2][j2] += aa[i2]*bb[j2];
    }
    __syncthreads();
  }
  int j0 = nb + tn*4;
  float* dst; const float* bptr; int col;
  if (j0 < 128){ dst = Qb; bptr = qb2; col = j0; }
  else if (j0 < 256){ dst = Kb; bptr = kb2; col = j0 - 128; }
  else { dst = Vb; bptr = vb2; col = j0 - 256; }
  float4 bi = *(const float4*)&bptr[col];
  #pragma unroll
  for (int mi = 0; mi < 4; ++mi){
    int m = mb + tm*4 + mi;
    float4 o;
    o.x = acc[mi][0] + bi.x; o.y = acc[mi][1] + bi.y;
    o.z = acc[mi][2] + bi.z; o.w = acc[mi][3] + bi.w;
    *(float4*)&dst[m*128 + col] = o;
  }
}

// ---------------- K7: a[b][s] = mean_t sigmoid(scale * Q[b,t,:].K[b,s,:])
__global__ __launch_bounds__(256) void k_attn(const float* __restrict__ Qb, const float* __restrict__ Kb,
        float* __restrict__ av){
  __shared__ float Ks[128*68];   // [k][s] pad 68
  __shared__ float Qs[128*36];   // [k][t] pad 36 (32-t chunks)
  __shared__ float asum[64];
  const int tid = threadIdx.x;
  const int st = blockIdx.x;   // 8 s-tiles of 64
  const int b  = blockIdx.y;   // 32
  const float SC = 0.08838834764831845f; // 128^-0.5
  for (int idx = tid; idx < 64*128; idx += 256){
    int s_l = idx >> 7, k = idx & 127;
    Ks[k*68 + s_l] = Kb[(size_t)(b*512 + st*64 + s_l)*128 + k];
  }
  if (tid < 64) asum[tid] = 0.f;
  __syncthreads();
  const int sl = tid & 15, tl = tid >> 4;
  float ps0 = 0.f, ps1 = 0.f, ps2 = 0.f, ps3 = 0.f;
  for (int tc = 0; tc < 16; ++tc){
    for (int idx = tid; idx < 32*128; idx += 256){
      int t_l = idx >> 7, k = idx & 127;
      Qs[k*36 + t_l] = Qb[(size_t)(b*512 + tc*32 + t_l)*128 + k];
    }
    __syncthreads();
    float a00=0,a01=0,a02=0,a03=0,a10=0,a11=0,a12=0,a13=0;
    #pragma unroll 4
    for (int k = 0; k < 128; ++k){
      float2 q2 = *(float2*)&Qs[k*36 + tl*2];
      float4 k4 = *(float4*)&Ks[k*68 + sl*4];
      a00 += q2.x*k4.x; a01 += q2.x*k4.y; a02 += q2.x*k4.z; a03 += q2.x*k4.w;
      a10 += q2.y*k4.x; a11 += q2.y*k4.y; a12 += q2.y*k4.z; a13 += q2.y*k4.w;
    }
    ps0 += fsigmoid(a00*SC) + fsigmoid(a10*SC);
    ps1 += fsigmoid(a01*SC) + fsigmoid(a11*SC);
    ps2 += fsigmoid(a02*SC) + fsigmoid(a12*SC);
    ps3 += fsigmoid(a03*SC) + fsigmoid(a13*SC);
    __syncthreads();
  }
  atomicAdd(&asum[sl*4+0], ps0);
  atomicAdd(&asum[sl*4+1], ps1);
  atomicAdd(&asum[sl*4+2], ps2);
  atomicAdd(&asum[sl*4+3], ps3);
  __syncthreads();
  if (tid < 64) av[b*512 + st*64 + tid] = asum[tid] * (1.f/512.f);
}

// ---------------- K8: out0[b][c] = sum_s a[b][s] * V[b][s][c]
__global__ __launch_bounds__(128) void k_av(const float* __restrict__ av, const float* __restrict__ Vb,
        float* __restrict__ out0){
  int b = blockIdx.x, c = threadIdx.x;
  float acc = 0.f;
  for (int s = 0; s < 512; ++s) acc += av[b*512 + s] * Vb[(size_t)(b*512 + s)*128 + c];
  out0[b*128 + c] = acc;
}

// ---------------- K9: BN3(batch) + head
__global__ __launch_bounds__(256) void k_final(const float* __restrict__ out0,
        const float* __restrict__ g3, const float* __restrict__ b3,
        const float* __restrict__ hw, const float* __restrict__ hb, float* __restrict__ out){
  __shared__ float on[32*132];
  const int tid = threadIdx.x;
  if (tid < 128){
    int c = tid;
    float s = 0.f;
    for (int bq = 0; bq < 32; ++bq) s += out0[bq*128 + c];
    float m = s * (1.f/32.f);
    float v = 0.f;
    for (int bq = 0; bq < 32; ++bq){ float d = out0[bq*128 + c] - m; v += d*d; }
    v *= (1.f/32.f);
    float sc = g3[c] * rsqrtf(v + EPSV);
    float sh = b3[c] - m*sc;
    for (int bq = 0; bq < 32; ++bq) on[bq*132 + c] = out0[bq*128 + c]*sc + sh;
  }
  __syncthreads();
  for (int o = tid; o < 32*96; o += 256){
    int bq = o / 96, hh = o - bq*96;
    float acc = hb[hh];
    for (int k = 0; k < 128; ++k) acc += on[bq*132 + k] * hw[hh*128 + k];
    out[o] = acc;
  }
}

extern "C" void kernel_launch(void* const* d_in, const int* in_sizes, int n_in,
                              void* d_out, int out_size, void* d_ws, size_t ws_size,
                              hipStream_t stream){
  const float* x      = (const float*)d_in[0];
  const float* conv_w = (const float*)d_in[1];
  const float* conv_b = (const float*)d_in[2];
  const float* bn1_g  = (const float*)d_in[3];
  const float* bn1_b  = (const float*)d_in[4];
  const float* beta1  = (const float*)d_in[5];
  const float* bn2_g  = (const float*)d_in[6];
  const float* bn2_b  = (const float*)d_in[7];
  const float* beta2  = (const float*)d_in[8];
  const float* g_wih  = (const float*)d_in[9];
  const float* g_whh  = (const float*)d_in[10];
  const float* g_bih  = (const float*)d_in[11];
  const float* g_bhh  = (const float*)d_in[12];
  const float* q_w    = (const float*)d_in[13];
  const float* q_b    = (const float*)d_in[14];
  const float* k_w    = (const float*)d_in[15];
  const float* k_b    = (const float*)d_in[16];
  const float* v_w    = (const float*)d_in[17];
  const float* v_b    = (const float*)d_in[18];
  const float* bn3_g  = (const float*)d_in[19];
  const float* bn3_b  = (const float*)d_in[20];
  const float* head_w = (const float*)d_in[21];
  const float* head_b = (const float*)d_in[22];

  char* ws = (char*)d_ws;
  float* hp  = (float*)ws;
  float* md  = (float*)(ws + 33554432);
  float* g   = (float*)(ws + 41943040);
  float* s1g = (float*)(ws + 50331648);
  float* s2g = (float*)(ws + 50331648 + 2048);
  float* a1  = (float*)(ws + 50331648 + 4096);
  float* b1  = (float*)(ws + 50331648 + 6144);
  float* av  = (float*)(ws + 50331648 + 8192);
  float* out0= (float*)(ws + 50331648 + 8192 + 65536);
  float* gi  = (float*)ws;                      // reuse (h_perm dead after k_lif)
  float* Qb  = (float*)ws;                      // reuse (gi dead after k_gru)
  float* Kb  = (float*)(ws + 8388608);
  float* Vb  = (float*)(ws + 16777216);

  hipMemsetAsync(ws + 50331648, 0, 4096, stream);  // zero BN1 accumulators

  k_conv<<<dim3(64, 16), 256, 0, stream>>>(x, conv_w, conv_b, hp, s1g, s2g);
  k_bn1<<<1, 512, 0, stream>>>(s1g, s2g, bn1_g, bn1_b, a1, b1);
  k_lif<<<16, 256, 0, stream>>>(hp, a1, b1, beta1, bn2_g, bn2_b, beta2, md);
  k_gemm_gi<<<dim3(256, 6), 256, 0, stream>>>(x, md, g_wih, g_bih, gi);
  k_gru<<<32, 256, 0, stream>>>(gi, g_whh, g_bhh, g);
  k_gemm_qkv<<<dim3(256, 6), 256, 0, stream>>>(g, q_w, q_b, k_w, k_b, v_w, v_b, Qb, Kb, Vb);
  k_attn<<<dim3(8, 32), 256, 0, stream>>>(Qb, Kb, av);
  k_av<<<32, 128, 0, stream>>>(av, Vb, out0);
  k_final<<<1, 256, 0, stream>>>(out0, bn3_g, bn3_b, head_w, head_b, (float*)d_out);
}

// Round 4
// 847.278 us; speedup vs baseline: 1.1867x; 1.0664x over previous
//
#include <hip/hip_runtime.h>
#include <math.h>

#define EPSV 1e-5f

#if __has_builtin(__builtin_amdgcn_exp2f)
#define EXP2F(x) __builtin_amdgcn_exp2f(x)
#else
#define EXP2F(x) exp2f(x)
#endif
#if __has_builtin(__builtin_amdgcn_rcpf)
#define RCPF(x) __builtin_amdgcn_rcpf(x)
#else
#define RCPF(x) (1.0f/(x))
#endif

__device__ __forceinline__ float fsigmoid(float x){
  // 1/(1+2^(-x*log2e))  -- v_exp_f32 + v_rcp_f32, no libcalls
  return RCPF(1.0f + EXP2F(-1.4426950408889634f * x));
}
__device__ __forceinline__ float ftanh(float x){
  // tanh(x) = 1/(0.5 + 0.5*2^(-2x*log2e)) - 1
  return RCPF(0.5f + 0.5f * EXP2F(-2.8853900817779268f * x)) - 1.0f;
}

// ---------------- K1: conv1d (pad=1,K=3) + bias -> h_perm [s=t*4+ss][n][b], + BN1 partial stats
__global__ __launch_bounds__(256) void k_conv(const float* __restrict__ x, const float* __restrict__ w,
        const float* __restrict__ cb, float* __restrict__ hp, float* __restrict__ s1g, float* __restrict__ s2g){
  __shared__ float xs[32*321];   // [b][tt(10)][i(32)], b-stride 321 to dodge bank conflicts
  __shared__ float ws[32*97];    // [ss*8+nl][96], row stride 97
  __shared__ float bs[32];
  const int tid = threadIdx.x;
  const int t0 = blockIdx.x * 8;      // 64 t-tiles of 8
  const int n0 = blockIdx.y * 8;      // 16 n-groups of 8
  for (int idx = tid; idx < 32*10*32; idx += 256){
    int bq = idx / 320; int rem = idx - bq*320; int tt = rem >> 5; int i = rem & 31;
    int tg = t0 - 1 + tt;
    float v = 0.f;
    if (tg >= 0 && tg < 512) v = x[(bq*512 + tg)*32 + i];
    xs[bq*321 + tt*32 + i] = v;
  }
  for (int idx = tid; idx < 32*96; idx += 256){
    int row = idx / 96; int within = idx - row*96;
    int ss = row >> 3; int nl = row & 7;
    int c = ss*128 + n0 + nl;
    ws[row*97 + within] = w[c*96 + within];
  }
  if (tid < 32){
    int ss = tid >> 3, nl = tid & 7;
    bs[tid] = cb[ss*128 + n0 + nl];
  }
  __syncthreads();
  const int b = tid & 31;
  const int nl = tid >> 5;
  float acc[4][8];
  #pragma unroll
  for (int ss = 0; ss < 4; ++ss){
    float bv = bs[ss*8 + nl];
    #pragma unroll
    for (int t = 0; t < 8; ++t) acc[ss][t] = bv;
  }
  for (int i = 0; i < 32; ++i){
    #pragma unroll
    for (int k = 0; k < 3; ++k){
      float w0 = ws[(0*8+nl)*97 + i*3 + k];
      float w1 = ws[(1*8+nl)*97 + i*3 + k];
      float w2 = ws[(2*8+nl)*97 + i*3 + k];
      float w3 = ws[(3*8+nl)*97 + i*3 + k];
      #pragma unroll
      for (int t = 0; t < 8; ++t){
        float xv = xs[b*321 + (t+k)*32 + i];
        acc[0][t] += xv*w0; acc[1][t] += xv*w1; acc[2][t] += xv*w2; acc[3][t] += xv*w3;
      }
    }
  }
  #pragma unroll
  for (int ss = 0; ss < 4; ++ss){
    int n = n0 + nl;
    float s1 = 0.f, s2 = 0.f;
    #pragma unroll
    for (int t = 0; t < 8; ++t){
      float v = acc[ss][t];
      int s = (t0 + t)*4 + ss;
      hp[s*4096 + n*32 + b] = v;       // [s][n][b]
      s1 += v; s2 += v*v;
    }
    #pragma unroll
    for (int off = 1; off < 32; off <<= 1){
      s1 += __shfl_xor(s1, off);
      s2 += __shfl_xor(s2, off);
    }
    if (b == 0){
      int c = ss*128 + n;
      atomicAdd(&s1g[c], s1);
      atomicAdd(&s2g[c], s2);
    }
  }
}

// ---------------- K2: finalize BN1 -> a1[c], b1[c]
__global__ void k_bn1(const float* __restrict__ s1g, const float* __restrict__ s2g,
                      const float* __restrict__ g, const float* __restrict__ bb,
                      float* __restrict__ a1, float* __restrict__ b1){
  int c = threadIdx.x;  // 512
  float m = s1g[c] * (1.f/16384.f);
  float v = s2g[c] * (1.f/16384.f) - m*m;
  float sc = g[c] * rsqrtf(v + EPSV);
  a1[c] = sc;
  b1[c] = bb[c] - m*sc;
}

// ---------------- K3: fused BN1-apply + LIF1 + per-step BN2(batch) + LIF2 + TS-mean downsample
__global__ __launch_bounds__(256) void k_lif(const float* __restrict__ hp,
        const float* __restrict__ a1, const float* __restrict__ b1,
        const float* __restrict__ beta1, const float* __restrict__ g2v, const float* __restrict__ b2v,
        const float* __restrict__ beta2, float* __restrict__ md){
  const int tid = threadIdx.x;
  const int b = tid & 31;
  const int n = blockIdx.x * 8 + (tid >> 5);
  float a1r0 = a1[0*128+n], a1r1 = a1[1*128+n], a1r2 = a1[2*128+n], a1r3 = a1[3*128+n];
  float b1r0 = b1[0*128+n], b1r1 = b1[1*128+n], b1r2 = b1[2*128+n], b1r3 = b1[3*128+n];
  float be1 = fminf(fmaxf(beta1[n], 0.f), 0.99f);
  float be2 = fminf(fmaxf(beta2[n], 0.f), 0.99f);
  float g2 = g2v[n], bb2 = b2v[n];
  float m1 = 0.f, r1 = 0.f, m2 = 0.f, r2 = 0.f;
  const float* base = hp + n*32 + b;   // +s*4096
  float c0 = base[0], c1 = base[4096], c2 = base[2*4096], c3 = base[3*4096];

#define LIF_STEP(CV, A1R, B1R) { \
    float x1 = CV*A1R + B1R; \
    m1 = be1*m1 + x1 - r1; \
    bool sp = (m1 > 1.0f); \
    unsigned long long mk = __ballot(sp); \
    float spk = sp ? 1.f : 0.f; r1 = spk; \
    unsigned hf = (tid & 32) ? (unsigned)(mk >> 32) : (unsigned)mk; \
    float mean = (float)__popc(hf) * 0.03125f; \
    float var = mean - mean*mean; \
    float h2 = (spk - mean) * rsqrtf(var + EPSV) * g2 + bb2; \
    m2 = be2*m2 + h2 - r2; \
    r2 = (m2 > 1.0f) ? 1.f : 0.f; \
    accd += m2; }

  for (int t = 0; t < 512; ++t){
    float n0v = 0.f, n1v = 0.f, n2v = 0.f, n3v = 0.f;
    if (t < 511){
      const float* nb = base + (size_t)(t+1)*16384;
      n0v = nb[0]; n1v = nb[4096]; n2v = nb[2*4096]; n3v = nb[3*4096];
    }
    float accd = 0.f;
    LIF_STEP(c0, a1r0, b1r0)
    LIF_STEP(c1, a1r1, b1r1)
    LIF_STEP(c2, a1r2, b1r2)
    LIF_STEP(c3, a1r3, b1r3)
    md[(b*512 + t)*128 + n] = accd * 0.25f;
    c0 = n0v; c1 = n1v; c2 = n2v; c3 = n3v;
  }
#undef LIF_STEP
}

// ---------------- K4: gi = concat(x, mem_down) @ W_ih^T + b_ih   (M=16384, N=384, K=160)
__global__ __launch_bounds__(256) void k_gemm_gi(const float* __restrict__ x, const float* __restrict__ md,
        const float* __restrict__ wih, const float* __restrict__ bih, float* __restrict__ gi){
  __shared__ float As[16*68];
  __shared__ float Bs[16*68];
  const int tid = threadIdx.x;
  const int lk = tid & 15, lr = tid >> 4;
  const int tn = tid & 15, tm = tid >> 4;
  const int mb = blockIdx.x*64, nb = blockIdx.y*64;
  float acc[4][4] = {};
  for (int kc = 0; kc < 10; ++kc){
    int k0 = kc*16;
    #pragma unroll
    for (int p = 0; p < 4; ++p){
      int m = mb + lr + p*16;
      int k = k0 + lk;
      float v = (k < 32) ? x[m*32 + k] : md[m*128 + (k - 32)];
      As[lk*68 + lr + p*16] = v;
      int j = nb + lr + p*16;
      Bs[lk*68 + lr + p*16] = wih[j*160 + k];
    }
    __syncthreads();
    #pragma unroll
    for (int kk = 0; kk < 16; ++kk){
      float4 a4 = *(float4*)&As[kk*68 + tm*4];
      float4 b4 = *(float4*)&Bs[kk*68 + tn*4];
      float aa[4] = {a4.x, a4.y, a4.z, a4.w};
      float bb[4] = {b4.x, b4.y, b4.z, b4.w};
      #pragma unroll
      for (int i2 = 0; i2 < 4; ++i2)
        #pragma unroll
        for (int j2 = 0; j2 < 4; ++j2) acc[i2][j2] += aa[i2]*bb[j2];
    }
    __syncthreads();
  }
  float4 bi = *(const float4*)&bih[nb + tn*4];
  #pragma unroll
  for (int mi = 0; mi < 4; ++mi){
    int m = mb + tm*4 + mi;
    float4 o;
    o.x = acc[mi][0] + bi.x; o.y = acc[mi][1] + bi.y;
    o.z = acc[mi][2] + bi.z; o.w = acc[mi][3] + bi.w;
    *(float4*)&gi[m*384 + nb + tn*4] = o;
  }
}

// ---------------- K5: GRU recurrence v4.
// 32 blocks (1/batch), 512 threads = 8 waves. Thread (j = tid>>2, quarter = tid&3):
// 3 gate dots for output j over K-quarter (32 elems) -> only 96 weight VGPRs, fits the
// 256-VGPR budget of 2 waves/EU (__launch_bounds__(512,2)). Quarters combined with
// two shfl_xor levels. One barrier/step (double-buffered h); gi prefetched a step ahead.
__global__ __launch_bounds__(512, 2) void k_gru(const float* __restrict__ gi, const float* __restrict__ whh,
        const float* __restrict__ bhh, float* __restrict__ gout){
  const int b = blockIdx.x;
  const int tid = threadIdx.x;
  const int j = tid >> 2;
  const int quarter = tid & 3;
  const int k0 = quarter * 32;
  __shared__ float hs[2][132];
  float4 wr[8], wz[8], wn[8];
  #pragma unroll
  for (int q = 0; q < 8; ++q){
    wr[q] = *(const float4*)&whh[(size_t)(      j)*128 + k0 + q*4];
    wz[q] = *(const float4*)&whh[(size_t)(128 + j)*128 + k0 + q*4];
    wn[q] = *(const float4*)&whh[(size_t)(256 + j)*128 + k0 + q*4];
  }
  float bh_r = 0.f, bh_z = 0.f, bh_n = 0.f;
  float gir = 0.f, giz = 0.f, gin = 0.f;
  const float* gib = gi + (size_t)b*512*384;
  if (!quarter){
    bh_r = bhh[j]; bh_z = bhh[128+j]; bh_n = bhh[256+j];
    gir = gib[j]; giz = gib[128+j]; gin = gib[256+j];   // prefetch t=0
  }
  if (tid < 128) hs[0][tid] = 0.f;
  float hprev = 0.f;
  __syncthreads();
  for (int t = 0; t < 512; ++t){
    // prefetch gi for t+1 (hides HBM/L3 latency under the dot product)
    float ngir = 0.f, ngiz = 0.f, ngin = 0.f;
    if (!quarter && t < 511){
      const float* gp = gib + (size_t)(t+1)*384;
      ngir = gp[j]; ngiz = gp[128+j]; ngin = gp[256+j];
    }
    const float* hr = &hs[t & 1][k0];
    float ar = 0.f, az = 0.f, an = 0.f;
    #pragma unroll
    for (int q = 0; q < 8; ++q){
      float4 h4 = *(const float4*)&hr[q*4];
      ar += wr[q].x*h4.x + wr[q].y*h4.y + wr[q].z*h4.z + wr[q].w*h4.w;
      az += wz[q].x*h4.x + wz[q].y*h4.y + wz[q].z*h4.z + wz[q].w*h4.w;
      an += wn[q].x*h4.x + wn[q].y*h4.y + wn[q].z*h4.z + wn[q].w*h4.w;
    }
    ar += __shfl_xor(ar, 1); ar += __shfl_xor(ar, 2);
    az += __shfl_xor(az, 1); az += __shfl_xor(az, 2);
    an += __shfl_xor(an, 1); an += __shfl_xor(an, 2);
    if (!quarter){
      float r = fsigmoid(gir + ar + bh_r);
      float z = fsigmoid(giz + az + bh_z);
      float nn = ftanh(gin + r*(an + bh_n));
      float hn = (1.f - z)*nn + z*hprev;
      hprev = hn;
      hs[(t + 1) & 1][j] = hn;
      gout[((size_t)b*512 + t)*128 + j] = hn;
    }
    gir = ngir; giz = ngiz; gin = ngin;
    __syncthreads();
  }
}

// ---------------- K6: Q,K,V = g @ [qw;kw;vw]^T + bias  (M=16384, N=384, K=128)
__global__ __launch_bounds__(256) void k_gemm_qkv(const float* __restrict__ g,
        const float* __restrict__ qw, const float* __restrict__ qb2,
        const float* __restrict__ kw, const float* __restrict__ kb2,
        const float* __restrict__ vw, const float* __restrict__ vb2,
        float* __restrict__ Qb, float* __restrict__ Kb, float* __restrict__ Vb){
  __shared__ float As[16*68];
  __shared__ float Bs[16*68];
  const int tid = threadIdx.x;
  const int lk = tid & 15, lr = tid >> 4;
  const int tn = tid & 15, tm = tid >> 4;
  const int mb = blockIdx.x*64, nb = blockIdx.y*64;
  float acc[4][4] = {};
  for (int kc = 0; kc < 8; ++kc){
    int k0 = kc*16;
    #pragma unroll
    for (int p = 0; p < 4; ++p){
      int m = mb + lr + p*16;
      As[lk*68 + lr + p*16] = g[m*128 + k0 + lk];
      int j = nb + lr + p*16;
      const float* wr = (j < 128) ? &qw[j*128] : (j < 256) ? &kw[(j-128)*128] : &vw[(j-256)*128];
      Bs[lk*68 + lr + p*16] = wr[k0 + lk];
    }
    __syncthreads();
    #pragma unroll
    for (int kk = 0; kk < 16; ++kk){
      float4 a4 = *(float4*)&As[kk*68 + tm*4];
      float4 b4 = *(float4*)&Bs[kk*68 + tn*4];
      float aa[4] = {a4.x, a4.y, a4.z, a4.w};
      float bb[4] = {b4.x, b4.y, b4.z, b4.w};
      #pragma unroll
      for (int i2 = 0; i2 < 4; ++i2)
        #pragma unroll
        for (int j2 = 0; j2 < 4; ++j2) acc[i2][j2] += aa[i2]*bb[j2];
    }
    __syncthreads();
  }
  int j0 = nb + tn*4;
  float* dst; const float* bptr; int col;
  if (j0 < 128){ dst = Qb; bptr = qb2; col = j0; }
  else if (j0 < 256){ dst = Kb; bptr = kb2; col = j0 - 128; }
  else { dst = Vb; bptr = vb2; col = j0 - 256; }
  float4 bi = *(const float4*)&bptr[col];
  #pragma unroll
  for (int mi = 0; mi < 4; ++mi){
    int m = mb + tm*4 + mi;
    float4 o;
    o.x = acc[mi][0] + bi.x; o.y = acc[mi][1] + bi.y;
    o.z = acc[mi][2] + bi.z; o.w = acc[mi][3] + bi.w;
    *(float4*)&dst[m*128 + col] = o;
  }
}

// ---------------- K7: a[b][s] = mean_t sigmoid(scale * Q[b,t,:].K[b,s,:])
__global__ __launch_bounds__(256) void k_attn(const float* __restrict__ Qb, const float* __restrict__ Kb,
        float* __restrict__ av){
  __shared__ float Ks[128*68];   // [k][s] pad 68
  __shared__ float Qs[128*36];   // [k][t] pad 36 (32-t chunks)
  __shared__ float asum[64];
  const int tid = threadIdx.x;
  const int st = blockIdx.x;   // 8 s-tiles of 64
  const int b  = blockIdx.y;   // 32
  const float SC = 0.08838834764831845f; // 128^-0.5
  for (int idx = tid; idx < 64*128; idx += 256){
    int s_l = idx >> 7, k = idx & 127;
    Ks[k*68 + s_l] = Kb[(size_t)(b*512 + st*64 + s_l)*128 + k];
  }
  if (tid < 64) asum[tid] = 0.f;
  __syncthreads();
  const int sl = tid & 15, tl = tid >> 4;
  float ps0 = 0.f, ps1 = 0.f, ps2 = 0.f, ps3 = 0.f;
  for (int tc = 0; tc < 16; ++tc){
    for (int idx = tid; idx < 32*128; idx += 256){
      int t_l = idx >> 7, k = idx & 127;
      Qs[k*36 + t_l] = Qb[(size_t)(b*512 + tc*32 + t_l)*128 + k];
    }
    __syncthreads();
    float a00=0,a01=0,a02=0,a03=0,a10=0,a11=0,a12=0,a13=0;
    #pragma unroll 4
    for (int k = 0; k < 128; ++k){
      float2 q2 = *(float2*)&Qs[k*36 + tl*2];
      float4 k4 = *(float4*)&Ks[k*68 + sl*4];
      a00 += q2.x*k4.x; a01 += q2.x*k4.y; a02 += q2.x*k4.z; a03 += q2.x*k4.w;
      a10 += q2.y*k4.x; a11 += q2.y*k4.y; a12 += q2.y*k4.z; a13 += q2.y*k4.w;
    }
    ps0 += fsigmoid(a00*SC) + fsigmoid(a10*SC);
    ps1 += fsigmoid(a01*SC) + fsigmoid(a11*SC);
    ps2 += fsigmoid(a02*SC) + fsigmoid(a12*SC);
    ps3 += fsigmoid(a03*SC) + fsigmoid(a13*SC);
    __syncthreads();
  }
  atomicAdd(&asum[sl*4+0], ps0);
  atomicAdd(&asum[sl*4+1], ps1);
  atomicAdd(&asum[sl*4+2], ps2);
  atomicAdd(&asum[sl*4+3], ps3);
  __syncthreads();
  if (tid < 64) av[b*512 + st*64 + tid] = asum[tid] * (1.f/512.f);
}

// ---------------- K8: out0[b][c] = sum_s a[b][s] * V[b][s][c]
__global__ __launch_bounds__(128) void k_av(const float* __restrict__ av, const float* __restrict__ Vb,
        float* __restrict__ out0){
  int b = blockIdx.x, c = threadIdx.x;
  float acc = 0.f;
  for (int s = 0; s < 512; ++s) acc += av[b*512 + s] * Vb[(size_t)(b*512 + s)*128 + c];
  out0[b*128 + c] = acc;
}

// ---------------- K9: BN3(batch) + head
__global__ __launch_bounds__(256) void k_final(const float* __restrict__ out0,
        const float* __restrict__ g3, const float* __restrict__ b3,
        const float* __restrict__ hw, const float* __restrict__ hb, float* __restrict__ out){
  __shared__ float on[32*132];
  const int tid = threadIdx.x;
  if (tid < 128){
    int c = tid;
    float s = 0.f;
    for (int bq = 0; bq < 32; ++bq) s += out0[bq*128 + c];
    float m = s * (1.f/32.f);
    float v = 0.f;
    for (int bq = 0; bq < 32; ++bq){ float d = out0[bq*128 + c] - m; v += d*d; }
    v *= (1.f/32.f);
    float sc = g3[c] * rsqrtf(v + EPSV);
    float sh = b3[c] - m*sc;
    for (int bq = 0; bq < 32; ++bq) on[bq*132 + c] = out0[bq*128 + c]*sc + sh;
  }
  __syncthreads();
  for (int o = tid; o < 32*96; o += 256){
    int bq = o / 96, hh = o - bq*96;
    float acc = hb[hh];
    for (int k = 0; k < 128; ++k) acc += on[bq*132 + k] * hw[hh*128 + k];
    out[o] = acc;
  }
}

extern "C" void kernel_launch(void* const* d_in, const int* in_sizes, int n_in,
                              void* d_out, int out_size, void* d_ws, size_t ws_size,
                              hipStream_t stream){
  const float* x      = (const float*)d_in[0];
  const float* conv_w = (const float*)d_in[1];
  const float* conv_b = (const float*)d_in[2];
  const float* bn1_g  = (const float*)d_in[3];
  const float* bn1_b  = (const float*)d_in[4];
  const float* beta1  = (const float*)d_in[5];
  const float* bn2_g  = (const float*)d_in[6];
  const float* bn2_b  = (const float*)d_in[7];
  const float* beta2  = (const float*)d_in[8];
  const float* g_wih  = (const float*)d_in[9];
  const float* g_whh  = (const float*)d_in[10];
  const float* g_bih  = (const float*)d_in[11];
  const float* g_bhh  = (const float*)d_in[12];
  const float* q_w    = (const float*)d_in[13];
  const float* q_b    = (const float*)d_in[14];
  const float* k_w    = (const float*)d_in[15];
  const float* k_b    = (const float*)d_in[16];
  const float* v_w    = (const float*)d_in[17];
  const float* v_b    = (const float*)d_in[18];
  const float* bn3_g  = (const float*)d_in[19];
  const float* bn3_b  = (const float*)d_in[20];
  const float* head_w = (const float*)d_in[21];
  const float* head_b = (const float*)d_in[22];

  char* ws = (char*)d_ws;
  float* hp  = (float*)ws;
  float* md  = (float*)(ws + 33554432);
  float* g   = (float*)(ws + 41943040);
  float* s1g = (float*)(ws + 50331648);
  float* s2g = (float*)(ws + 50331648 + 2048);
  float* a1  = (float*)(ws + 50331648 + 4096);
  float* b1  = (float*)(ws + 50331648 + 6144);
  float* av  = (float*)(ws + 50331648 + 8192);
  float* out0= (float*)(ws + 50331648 + 8192 + 65536);
  float* gi  = (float*)ws;                      // reuse (h_perm dead after k_lif)
  float* Qb  = (float*)ws;                      // reuse (gi dead after k_gru)
  float* Kb  = (float*)(ws + 8388608);
  float* Vb  = (float*)(ws + 16777216);

  hipMemsetAsync(ws + 50331648, 0, 4096, stream);  // zero BN1 accumulators

  k_conv<<<dim3(64, 16), 256, 0, stream>>>(x, conv_w, conv_b, hp, s1g, s2g);
  k_bn1<<<1, 512, 0, stream>>>(s1g, s2g, bn1_g, bn1_b, a1, b1);
  k_lif<<<16, 256, 0, stream>>>(hp, a1, b1, beta1, bn2_g, bn2_b, beta2, md);
  k_gemm_gi<<<dim3(256, 6), 256, 0, stream>>>(x, md, g_wih, g_bih, gi);
  k_gru<<<32, 512, 0, stream>>>(gi, g_whh, g_bhh, g);
  k_gemm_qkv<<<dim3(256, 6), 256, 0, stream>>>(g, q_w, q_b, k_w, k_b, v_w, v_b, Qb, Kb, Vb);
  k_attn<<<dim3(8, 32), 256, 0, stream>>>(Qb, Kb, av);
  k_av<<<32, 128, 0, stream>>>(av, Vb, out0);
  k_final<<<1, 256, 0, stream>>>(out0, bn3_g, bn3_b, head_w, head_b, (float*)d_out);
}

// Round 5
// 841.674 us; speedup vs baseline: 1.1946x; 1.0067x over previous
//
#include <hip/hip_runtime.h>
#include <math.h>

#define EPSV 1e-5f

#if __has_builtin(__builtin_amdgcn_exp2f)
#define EXP2F(x) __builtin_amdgcn_exp2f(x)
#else
#define EXP2F(x) exp2f(x)
#endif
#if __has_builtin(__builtin_amdgcn_rcpf)
#define RCPF(x) __builtin_amdgcn_rcpf(x)
#else
#define RCPF(x) (1.0f/(x))
#endif

__device__ __forceinline__ float fsigmoid(float x){
  return RCPF(1.0f + EXP2F(-1.4426950408889634f * x));
}
__device__ __forceinline__ float ftanh(float x){
  return RCPF(0.5f + 0.5f * EXP2F(-2.8853900817779268f * x)) - 1.0f;
}

// ---------------- K1: conv1d (pad=1,K=3) + bias -> h_perm [s=t*4+ss][n][b], + BN1 partial stats
__global__ __launch_bounds__(256) void k_conv(const float* __restrict__ x, const float* __restrict__ w,
        const float* __restrict__ cb, float* __restrict__ hp, float* __restrict__ s1g, float* __restrict__ s2g){
  __shared__ float xs[32*321];   // [b][tt(10)][i(32)], b-stride 321 to dodge bank conflicts
  __shared__ float ws[32*97];    // [ss*8+nl][96], row stride 97
  __shared__ float bs[32];
  const int tid = threadIdx.x;
  const int t0 = blockIdx.x * 8;      // 64 t-tiles of 8
  const int n0 = blockIdx.y * 8;      // 16 n-groups of 8
  for (int idx = tid; idx < 32*10*32; idx += 256){
    int bq = idx / 320; int rem = idx - bq*320; int tt = rem >> 5; int i = rem & 31;
    int tg = t0 - 1 + tt;
    float v = 0.f;
    if (tg >= 0 && tg < 512) v = x[(bq*512 + tg)*32 + i];
    xs[bq*321 + tt*32 + i] = v;
  }
  for (int idx = tid; idx < 32*96; idx += 256){
    int row = idx / 96; int within = idx - row*96;
    int ss = row >> 3; int nl = row & 7;
    int c = ss*128 + n0 + nl;
    ws[row*97 + within] = w[c*96 + within];
  }
  if (tid < 32){
    int ss = tid >> 3, nl = tid & 7;
    bs[tid] = cb[ss*128 + n0 + nl];
  }
  __syncthreads();
  const int b = tid & 31;
  const int nl = tid >> 5;
  float acc[4][8];
  #pragma unroll
  for (int ss = 0; ss < 4; ++ss){
    float bv = bs[ss*8 + nl];
    #pragma unroll
    for (int t = 0; t < 8; ++t) acc[ss][t] = bv;
  }
  for (int i = 0; i < 32; ++i){
    #pragma unroll
    for (int k = 0; k < 3; ++k){
      float w0 = ws[(0*8+nl)*97 + i*3 + k];
      float w1 = ws[(1*8+nl)*97 + i*3 + k];
      float w2 = ws[(2*8+nl)*97 + i*3 + k];
      float w3 = ws[(3*8+nl)*97 + i*3 + k];
      #pragma unroll
      for (int t = 0; t < 8; ++t){
        float xv = xs[b*321 + (t+k)*32 + i];
        acc[0][t] += xv*w0; acc[1][t] += xv*w1; acc[2][t] += xv*w2; acc[3][t] += xv*w3;
      }
    }
  }
  #pragma unroll
  for (int ss = 0; ss < 4; ++ss){
    int n = n0 + nl;
    float s1 = 0.f, s2 = 0.f;
    #pragma unroll
    for (int t = 0; t < 8; ++t){
      float v = acc[ss][t];
      int s = (t0 + t)*4 + ss;
      hp[s*4096 + n*32 + b] = v;       // [s][n][b]
      s1 += v; s2 += v*v;
    }
    #pragma unroll
    for (int off = 1; off < 32; off <<= 1){
      s1 += __shfl_xor(s1, off);
      s2 += __shfl_xor(s2, off);
    }
    if (b == 0){
      int c = ss*128 + n;
      atomicAdd(&s1g[c], s1);
      atomicAdd(&s2g[c], s2);
    }
  }
}

// ---------------- K2: finalize BN1 -> a1[c], b1[c]
__global__ void k_bn1(const float* __restrict__ s1g, const float* __restrict__ s2g,
                      const float* __restrict__ g, const float* __restrict__ bb,
                      float* __restrict__ a1, float* __restrict__ b1){
  int c = threadIdx.x;  // 512
  float m = s1g[c] * (1.f/16384.f);
  float v = s2g[c] * (1.f/16384.f) - m*m;
  float sc = g[c] * rsqrtf(v + EPSV);
  a1[c] = sc;
  b1[c] = bb[c] - m*sc;
}

// ---------------- K3: fused BN1-apply + LIF1 + per-step BN2(batch) + LIF2 + TS-mean downsample
__global__ __launch_bounds__(256) void k_lif(const float* __restrict__ hp,
        const float* __restrict__ a1, const float* __restrict__ b1,
        const float* __restrict__ beta1, const float* __restrict__ g2v, const float* __restrict__ b2v,
        const float* __restrict__ beta2, float* __restrict__ md){
  const int tid = threadIdx.x;
  const int b = tid & 31;
  const int n = blockIdx.x * 8 + (tid >> 5);
  float a1r0 = a1[0*128+n], a1r1 = a1[1*128+n], a1r2 = a1[2*128+n], a1r3 = a1[3*128+n];
  float b1r0 = b1[0*128+n], b1r1 = b1[1*128+n], b1r2 = b1[2*128+n], b1r3 = b1[3*128+n];
  float be1 = fminf(fmaxf(beta1[n], 0.f), 0.99f);
  float be2 = fminf(fmaxf(beta2[n], 0.f), 0.99f);
  float g2 = g2v[n], bb2 = b2v[n];
  float m1 = 0.f, r1 = 0.f, m2 = 0.f, r2 = 0.f;
  const float* base = hp + n*32 + b;   // +s*4096
  float c0 = base[0], c1 = base[4096], c2 = base[2*4096], c3 = base[3*4096];

#define LIF_STEP(CV, A1R, B1R) { \
    float x1 = CV*A1R + B1R; \
    m1 = be1*m1 + x1 - r1; \
    bool sp = (m1 > 1.0f); \
    unsigned long long mk = __ballot(sp); \
    float spk = sp ? 1.f : 0.f; r1 = spk; \
    unsigned hf = (tid & 32) ? (unsigned)(mk >> 32) : (unsigned)mk; \
    float mean = (float)__popc(hf) * 0.03125f; \
    float var = mean - mean*mean; \
    float h2 = (spk - mean) * rsqrtf(var + EPSV) * g2 + bb2; \
    m2 = be2*m2 + h2 - r2; \
    r2 = (m2 > 1.0f) ? 1.f : 0.f; \
    accd += m2; }

  for (int t = 0; t < 512; ++t){
    float n0v = 0.f, n1v = 0.f, n2v = 0.f, n3v = 0.f;
    if (t < 511){
      const float* nb = base + (size_t)(t+1)*16384;
      n0v = nb[0]; n1v = nb[4096]; n2v = nb[2*4096]; n3v = nb[3*4096];
    }
    float accd = 0.f;
    LIF_STEP(c0, a1r0, b1r0)
    LIF_STEP(c1, a1r1, b1r1)
    LIF_STEP(c2, a1r2, b1r2)
    LIF_STEP(c3, a1r3, b1r3)
    md[(b*512 + t)*128 + n] = accd * 0.25f;
    c0 = n0v; c1 = n1v; c2 = n2v; c3 = n3v;
  }
#undef LIF_STEP
}

// ---------------- K4: gi = concat(x, mem_down) @ W_ih^T + b_ih   (M=16384, N=384, K=160)
__global__ __launch_bounds__(256) void k_gemm_gi(const float* __restrict__ x, const float* __restrict__ md,
        const float* __restrict__ wih, const float* __restrict__ bih, float* __restrict__ gi){
  __shared__ float As[16*68];
  __shared__ float Bs[16*68];
  const int tid = threadIdx.x;
  const int lk = tid & 15, lr = tid >> 4;
  const int tn = tid & 15, tm = tid >> 4;
  const int mb = blockIdx.x*64, nb = blockIdx.y*64;
  float acc[4][4] = {};
  for (int kc = 0; kc < 10; ++kc){
    int k0 = kc*16;
    #pragma unroll
    for (int p = 0; p < 4; ++p){
      int m = mb + lr + p*16;
      int k = k0 + lk;
      float v = (k < 32) ? x[m*32 + k] : md[m*128 + (k - 32)];
      As[lk*68 + lr + p*16] = v;
      int j = nb + lr + p*16;
      Bs[lk*68 + lr + p*16] = wih[j*160 + k];
    }
    __syncthreads();
    #pragma unroll
    for (int kk = 0; kk < 16; ++kk){
      float4 a4 = *(float4*)&As[kk*68 + tm*4];
      float4 b4 = *(float4*)&Bs[kk*68 + tn*4];
      float aa[4] = {a4.x, a4.y, a4.z, a4.w};
      float bb[4] = {b4.x, b4.y, b4.z, b4.w};
      #pragma unroll
      for (int i2 = 0; i2 < 4; ++i2)
        #pragma unroll
        for (int j2 = 0; j2 < 4; ++j2) acc[i2][j2] += aa[i2]*bb[j2];
    }
    __syncthreads();
  }
  float4 bi = *(const float4*)&bih[nb + tn*4];
  #pragma unroll
  for (int mi = 0; mi < 4; ++mi){
    int m = mb + tm*4 + mi;
    float4 o;
    o.x = acc[mi][0] + bi.x; o.y = acc[mi][1] + bi.y;
    o.z = acc[mi][2] + bi.z; o.w = acc[mi][3] + bi.w;
    *(float4*)&gi[m*384 + nb + tn*4] = o;
  }
}

// ---------------- K5: GRU recurrence v5.
// 32 blocks (1/batch), 512 threads. Thread (j = tid>>2, quarter = tid&3): 3 gate dots over
// a K-quarter (32 elems) = 24 float4 weights in NAMED registers, pinned via asm so the RA
// cannot rematerialize the (invariant) loads inside the loop. hs[2][4][36]: broadcast reads,
// disjoint bank groups per quarter. One barrier/step; gi prefetched a step ahead.
#define KEEP4(v) asm volatile("" : "+v"(v.x), "+v"(v.y), "+v"(v.z), "+v"(v.w))
#define FMA4(W,H) (W.x*H.x + W.y*H.y + W.z*H.z + W.w*H.w)
__global__ __launch_bounds__(512, 2) void k_gru(const float* __restrict__ gi, const float* __restrict__ whh,
        const float* __restrict__ bhh, float* __restrict__ gout){
  const int b = blockIdx.x;
  const int tid = threadIdx.x;
  const int j = tid >> 2;
  const int quarter = tid & 3;
  __shared__ float hs[2][4][36];   // [buf][quarter][32+4 pad]
  const float* wbr = &whh[(size_t)(      j)*128 + quarter*32];
  const float* wbz = &whh[(size_t)(128 + j)*128 + quarter*32];
  const float* wbn = &whh[(size_t)(256 + j)*128 + quarter*32];
  float4 wr0 = *(const float4*)(wbr+ 0), wr1 = *(const float4*)(wbr+ 4),
         wr2 = *(const float4*)(wbr+ 8), wr3 = *(const float4*)(wbr+12),
         wr4 = *(const float4*)(wbr+16), wr5 = *(const float4*)(wbr+20),
         wr6 = *(const float4*)(wbr+24), wr7 = *(const float4*)(wbr+28);
  float4 wz0 = *(const float4*)(wbz+ 0), wz1 = *(const float4*)(wbz+ 4),
         wz2 = *(const float4*)(wbz+ 8), wz3 = *(const float4*)(wbz+12),
         wz4 = *(const float4*)(wbz+16), wz5 = *(const float4*)(wbz+20),
         wz6 = *(const float4*)(wbz+24), wz7 = *(const float4*)(wbz+28);
  float4 wn0 = *(const float4*)(wbn+ 0), wn1 = *(const float4*)(wbn+ 4),
         wn2 = *(const float4*)(wbn+ 8), wn3 = *(const float4*)(wbn+12),
         wn4 = *(const float4*)(wbn+16), wn5 = *(const float4*)(wbn+20),
         wn6 = *(const float4*)(wbn+24), wn7 = *(const float4*)(wbn+28);
  KEEP4(wr0); KEEP4(wr1); KEEP4(wr2); KEEP4(wr3); KEEP4(wr4); KEEP4(wr5); KEEP4(wr6); KEEP4(wr7);
  KEEP4(wz0); KEEP4(wz1); KEEP4(wz2); KEEP4(wz3); KEEP4(wz4); KEEP4(wz5); KEEP4(wz6); KEEP4(wz7);
  KEEP4(wn0); KEEP4(wn1); KEEP4(wn2); KEEP4(wn3); KEEP4(wn4); KEEP4(wn5); KEEP4(wn6); KEEP4(wn7);
  float bh_r = 0.f, bh_z = 0.f, bh_n = 0.f;
  float gir = 0.f, giz = 0.f, gin = 0.f;
  const float* gib = gi + (size_t)b*512*384;
  if (!quarter){
    bh_r = bhh[j]; bh_z = bhh[128+j]; bh_n = bhh[256+j];
    gir = gib[j]; giz = gib[128+j]; gin = gib[256+j];   // prefetch t=0
  }
  if (tid < 128) hs[0][tid >> 5][tid & 31] = 0.f;
  float hprev = 0.f;
  __syncthreads();
  for (int t = 0; t < 512; ++t){
    // prefetch gi for t+1 (hides HBM/L3 latency under the dot product)
    float ngir = 0.f, ngiz = 0.f, ngin = 0.f;
    if (!quarter && t < 511){
      const float* gp = gib + (size_t)(t+1)*384;
      ngir = gp[j]; ngiz = gp[128+j]; ngin = gp[256+j];
    }
    const float* hq = &hs[t & 1][quarter][0];
    float4 h0 = *(const float4*)(hq+ 0), h1 = *(const float4*)(hq+ 4),
           h2 = *(const float4*)(hq+ 8), h3 = *(const float4*)(hq+12),
           h4 = *(const float4*)(hq+16), h5 = *(const float4*)(hq+20),
           h6 = *(const float4*)(hq+24), h7 = *(const float4*)(hq+28);
    float ar = FMA4(wr0,h0) + FMA4(wr1,h1) + FMA4(wr2,h2) + FMA4(wr3,h3)
             + FMA4(wr4,h4) + FMA4(wr5,h5) + FMA4(wr6,h6) + FMA4(wr7,h7);
    float az = FMA4(wz0,h0) + FMA4(wz1,h1) + FMA4(wz2,h2) + FMA4(wz3,h3)
             + FMA4(wz4,h4) + FMA4(wz5,h5) + FMA4(wz6,h6) + FMA4(wz7,h7);
    float an = FMA4(wn0,h0) + FMA4(wn1,h1) + FMA4(wn2,h2) + FMA4(wn3,h3)
             + FMA4(wn4,h4) + FMA4(wn5,h5) + FMA4(wn6,h6) + FMA4(wn7,h7);
    ar += __shfl_xor(ar, 1); ar += __shfl_xor(ar, 2);
    az += __shfl_xor(az, 1); az += __shfl_xor(az, 2);
    an += __shfl_xor(an, 1); an += __shfl_xor(an, 2);
    if (!quarter){
      float r = fsigmoid(gir + ar + bh_r);
      float z = fsigmoid(giz + az + bh_z);
      float nn = ftanh(gin + r*(an + bh_n));
      float hn = (1.f - z)*nn + z*hprev;
      hprev = hn;
      hs[(t + 1) & 1][j >> 5][j & 31] = hn;
      gout[((size_t)b*512 + t)*128 + j] = hn;
    }
    gir = ngir; giz = ngiz; gin = ngin;
    __syncthreads();
  }
}
#undef KEEP4
#undef FMA4

// ---------------- K6: Q,K,V = g @ [qw;kw;vw]^T + bias  (M=16384, N=384, K=128)
__global__ __launch_bounds__(256) void k_gemm_qkv(const float* __restrict__ g,
        const float* __restrict__ qw, const float* __restrict__ qb2,
        const float* __restrict__ kw, const float* __restrict__ kb2,
        const float* __restrict__ vw, const float* __restrict__ vb2,
        float* __restrict__ Qb, float* __restrict__ Kb, float* __restrict__ Vb){
  __shared__ float As[16*68];
  __shared__ float Bs[16*68];
  const int tid = threadIdx.x;
  const int lk = tid & 15, lr = tid >> 4;
  const int tn = tid & 15, tm = tid >> 4;
  const int mb = blockIdx.x*64, nb = blockIdx.y*64;
  float acc[4][4] = {};
  for (int kc = 0; kc < 8; ++kc){
    int k0 = kc*16;
    #pragma unroll
    for (int p = 0; p < 4; ++p){
      int m = mb + lr + p*16;
      As[lk*68 + lr + p*16] = g[m*128 + k0 + lk];
      int j = nb + lr + p*16;
      const float* wr = (j < 128) ? &qw[j*128] : (j < 256) ? &kw[(j-128)*128] : &vw[(j-256)*128];
      Bs[lk*68 + lr + p*16] = wr[k0 + lk];
    }
    __syncthreads();
    #pragma unroll
    for (int kk = 0; kk < 16; ++kk){
      float4 a4 = *(float4*)&As[kk*68 + tm*4];
      float4 b4 = *(float4*)&Bs[kk*68 + tn*4];
      float aa[4] = {a4.x, a4.y, a4.z, a4.w};
      float bb[4] = {b4.x, b4.y, b4.z, b4.w};
      #pragma unroll
      for (int i2 = 0; i2 < 4; ++i2)
        #pragma unroll
        for (int j2 = 0; j2 < 4; ++j2) acc[i2][j2] += aa[i2]*bb[j2];
    }
    __syncthreads();
  }
  int j0 = nb + tn*4;
  float* dst; const float* bptr; int col;
  if (j0 < 128){ dst = Qb; bptr = qb2; col = j0; }
  else if (j0 < 256){ dst = Kb; bptr = kb2; col = j0 - 128; }
  else { dst = Vb; bptr = vb2; col = j0 - 256; }
  float4 bi = *(const float4*)&bptr[col];
  #pragma unroll
  for (int mi = 0; mi < 4; ++mi){
    int m = mb + tm*4 + mi;
    float4 o;
    o.x = acc[mi][0] + bi.x; o.y = acc[mi][1] + bi.y;
    o.z = acc[mi][2] + bi.z; o.w = acc[mi][3] + bi.w;
    *(float4*)&dst[m*128 + col] = o;
  }
}

// ---------------- K7: a[b][s] = mean_t sigmoid(scale * Q[b,t,:].K[b,s,:])
__global__ __launch_bounds__(256) void k_attn(const float* __restrict__ Qb, const float* __restrict__ Kb,
        float* __restrict__ av){
  __shared__ float Ks[128*68];   // [k][s] pad 68
  __shared__ float Qs[128*36];   // [k][t] pad 36 (32-t chunks)
  __shared__ float asum[64];
  const int tid = threadIdx.x;
  const int st = blockIdx.x;   // 8 s-tiles of 64
  const int b  = blockIdx.y;   // 32
  const float SC = 0.08838834764831845f; // 128^-0.5
  for (int idx = tid; idx < 64*128; idx += 256){
    int s_l = idx >> 7, k = idx & 127;
    Ks[k*68 + s_l] = Kb[(size_t)(b*512 + st*64 + s_l)*128 + k];
  }
  if (tid < 64) asum[tid] = 0.f;
  __syncthreads();
  const int sl = tid & 15, tl = tid >> 4;
  float ps0 = 0.f, ps1 = 0.f, ps2 = 0.f, ps3 = 0.f;
  for (int tc = 0; tc < 16; ++tc){
    for (int idx = tid; idx < 32*128; idx += 256){
      int t_l = idx >> 7, k = idx & 127;
      Qs[k*36 + t_l] = Qb[(size_t)(b*512 + tc*32 + t_l)*128 + k];
    }
    __syncthreads();
    float a00=0,a01=0,a02=0,a03=0,a10=0,a11=0,a12=0,a13=0;
    #pragma unroll 4
    for (int k = 0; k < 128; ++k){
      float2 q2 = *(float2*)&Qs[k*36 + tl*2];
      float4 k4 = *(float4*)&Ks[k*68 + sl*4];
      a00 += q2.x*k4.x; a01 += q2.x*k4.y; a02 += q2.x*k4.z; a03 += q2.x*k4.w;
      a10 += q2.y*k4.x; a11 += q2.y*k4.y; a12 += q2.y*k4.z; a13 += q2.y*k4.w;
    }
    ps0 += fsigmoid(a00*SC) + fsigmoid(a10*SC);
    ps1 += fsigmoid(a01*SC) + fsigmoid(a11*SC);
    ps2 += fsigmoid(a02*SC) + fsigmoid(a12*SC);
    ps3 += fsigmoid(a03*SC) + fsigmoid(a13*SC);
    __syncthreads();
  }
  atomicAdd(&asum[sl*4+0], ps0);
  atomicAdd(&asum[sl*4+1], ps1);
  atomicAdd(&asum[sl*4+2], ps2);
  atomicAdd(&asum[sl*4+3], ps3);
  __syncthreads();
  if (tid < 64) av[b*512 + st*64 + tid] = asum[tid] * (1.f/512.f);
}

// ---------------- K8: out0[b][c] = sum_s a[b][s] * V[b][s][c]
__global__ __launch_bounds__(128) void k_av(const float* __restrict__ av, const float* __restrict__ Vb,
        float* __restrict__ out0){
  int b = blockIdx.x, c = threadIdx.x;
  float acc = 0.f;
  for (int s = 0; s < 512; ++s) acc += av[b*512 + s] * Vb[(size_t)(b*512 + s)*128 + c];
  out0[b*128 + c] = acc;
}

// ---------------- K9: BN3(batch) + head
__global__ __launch_bounds__(256) void k_final(const float* __restrict__ out0,
        const float* __restrict__ g3, const float* __restrict__ b3,
        const float* __restrict__ hw, const float* __restrict__ hb, float* __restrict__ out){
  __shared__ float on[32*132];
  const int tid = threadIdx.x;
  if (tid < 128){
    int c = tid;
    float s = 0.f;
    for (int bq = 0; bq < 32; ++bq) s += out0[bq*128 + c];
    float m = s * (1.f/32.f);
    float v = 0.f;
    for (int bq = 0; bq < 32; ++bq){ float d = out0[bq*128 + c] - m; v += d*d; }
    v *= (1.f/32.f);
    float sc = g3[c] * rsqrtf(v + EPSV);
    float sh = b3[c] - m*sc;
    for (int bq = 0; bq < 32; ++bq) on[bq*132 + c] = out0[bq*128 + c]*sc + sh;
  }
  __syncthreads();
  for (int o = tid; o < 32*96; o += 256){
    int bq = o / 96, hh = o - bq*96;
    float acc = hb[hh];
    for (int k = 0; k < 128; ++k) acc += on[bq*132 + k] * hw[hh*128 + k];
    out[o] = acc;
  }
}

extern "C" void kernel_launch(void* const* d_in, const int* in_sizes, int n_in,
                              void* d_out, int out_size, void* d_ws, size_t ws_size,
                              hipStream_t stream){
  const float* x      = (const float*)d_in[0];
  const float* conv_w = (const float*)d_in[1];
  const float* conv_b = (const float*)d_in[2];
  const float* bn1_g  = (const float*)d_in[3];
  const float* bn1_b  = (const float*)d_in[4];
  const float* beta1  = (const float*)d_in[5];
  const float* bn2_g  = (const float*)d_in[6];
  const float* bn2_b  = (const float*)d_in[7];
  const float* beta2  = (const float*)d_in[8];
  const float* g_wih  = (const float*)d_in[9];
  const float* g_whh  = (const float*)d_in[10];
  const float* g_bih  = (const float*)d_in[11];
  const float* g_bhh  = (const float*)d_in[12];
  const float* q_w    = (const float*)d_in[13];
  const float* q_b    = (const float*)d_in[14];
  const float* k_w    = (const float*)d_in[15];
  const float* k_b    = (const float*)d_in[16];
  const float* v_w    = (const float*)d_in[17];
  const float* v_b    = (const float*)d_in[18];
  const float* bn3_g  = (const float*)d_in[19];
  const float* bn3_b  = (const float*)d_in[20];
  const float* head_w = (const float*)d_in[21];
  const float* head_b = (const float*)d_in[22];

  char* ws = (char*)d_ws;
  float* hp  = (float*)ws;
  float* md  = (float*)(ws + 33554432);
  float* g   = (float*)(ws + 41943040);
  float* s1g = (float*)(ws + 50331648);
  float* s2g = (float*)(ws + 50331648 + 2048);
  float* a1  = (float*)(ws + 50331648 + 4096);
  float* b1  = (float*)(ws + 50331648 + 6144);
  float* av  = (float*)(ws + 50331648 + 8192);
  float* out0= (float*)(ws + 50331648 + 8192 + 65536);
  float* gi  = (float*)ws;                      // reuse (h_perm dead after k_lif)
  float* Qb  = (float*)ws;                      // reuse (gi dead after k_gru)
  float* Kb  = (float*)(ws + 8388608);
  float* Vb  = (float*)(ws + 16777216);

  hipMemsetAsync(ws + 50331648, 0, 4096, stream);  // zero BN1 accumulators

  k_conv<<<dim3(64, 16), 256, 0, stream>>>(x, conv_w, conv_b, hp, s1g, s2g);
  k_bn1<<<1, 512, 0, stream>>>(s1g, s2g, bn1_g, bn1_b, a1, b1);
  k_lif<<<16, 256, 0, stream>>>(hp, a1, b1, beta1, bn2_g, bn2_b, beta2, md);
  k_gemm_gi<<<dim3(256, 6), 256, 0, stream>>>(x, md, g_wih, g_bih, gi);
  k_gru<<<32, 512, 0, stream>>>(gi, g_whh, g_bhh, g);
  k_gemm_qkv<<<dim3(256, 6), 256, 0, stream>>>(g, q_w, q_b, k_w, k_b, v_w, v_b, Qb, Kb, Vb);
  k_attn<<<dim3(8, 32), 256, 0, stream>>>(Qb, Kb, av);
  k_av<<<32, 128, 0, stream>>>(av, Vb, out0);
  k_final<<<1, 256, 0, stream>>>(out0, bn3_g, bn3_b, head_w, head_b, (float*)d_out);
}

// Round 7
// 720.067 us; speedup vs baseline: 1.3964x; 1.1689x over previous
//
#include <hip/hip_runtime.h>
#include <math.h>

#define EPSV 1e-5f

#if __has_builtin(__builtin_amdgcn_exp2f)
#define EXP2F(x) __builtin_amdgcn_exp2f(x)
#else
#define EXP2F(x) exp2f(x)
#endif
#if __has_builtin(__builtin_amdgcn_rcpf)
#define RCPF(x) __builtin_amdgcn_rcpf(x)
#else
#define RCPF(x) (1.0f/(x))
#endif

__device__ __forceinline__ float fsigmoid(float x){
  return RCPF(1.0f + EXP2F(-1.4426950408889634f * x));
}
__device__ __forceinline__ float ftanh(float x){
  return RCPF(0.5f + 0.5f * EXP2F(-2.8853900817779268f * x)) - 1.0f;
}
__device__ __forceinline__ unsigned short f2bf(float f){
  unsigned u = __float_as_uint(f);
  return (unsigned short)((u + 0x7FFFu + ((u >> 16) & 1u)) >> 16);
}

typedef __attribute__((ext_vector_type(8))) short bf16x8;
typedef __attribute__((ext_vector_type(4))) float f32x4;

// ---------------- K1: conv1d (pad=1,K=3) + bias -> h_perm [s=t*4+ss][n][b], + BN1 partial stats
__global__ __launch_bounds__(256) void k_conv(const float* __restrict__ x, const float* __restrict__ w,
        const float* __restrict__ cb, float* __restrict__ hp, float* __restrict__ s1g, float* __restrict__ s2g){
  __shared__ float xs[32*321];   // [b][tt(10)][i(32)], b-stride 321 to dodge bank conflicts
  __shared__ float ws[32*97];    // [ss*8+nl][96], row stride 97
  __shared__ float bs[32];
  const int tid = threadIdx.x;
  const int t0 = blockIdx.x * 8;      // 64 t-tiles of 8
  const int n0 = blockIdx.y * 8;      // 16 n-groups of 8
  for (int idx = tid; idx < 32*10*32; idx += 256){
    int bq = idx / 320; int rem = idx - bq*320; int tt = rem >> 5; int i = rem & 31;
    int tg = t0 - 1 + tt;
    float v = 0.f;
    if (tg >= 0 && tg < 512) v = x[(bq*512 + tg)*32 + i];
    xs[bq*321 + tt*32 + i] = v;
  }
  for (int idx = tid; idx < 32*96; idx += 256){
    int row = idx / 96; int within = idx - row*96;
    int ss = row >> 3; int nl = row & 7;
    int c = ss*128 + n0 + nl;
    ws[row*97 + within] = w[c*96 + within];
  }
  if (tid < 32){
    int ss = tid >> 3, nl = tid & 7;
    bs[tid] = cb[ss*128 + n0 + nl];
  }
  __syncthreads();
  const int b = tid & 31;
  const int nl = tid >> 5;
  float acc[4][8];
  #pragma unroll
  for (int ss = 0; ss < 4; ++ss){
    float bv = bs[ss*8 + nl];
    #pragma unroll
    for (int t = 0; t < 8; ++t) acc[ss][t] = bv;
  }
  for (int i = 0; i < 32; ++i){
    #pragma unroll
    for (int k = 0; k < 3; ++k){
      float w0 = ws[(0*8+nl)*97 + i*3 + k];
      float w1 = ws[(1*8+nl)*97 + i*3 + k];
      float w2 = ws[(2*8+nl)*97 + i*3 + k];
      float w3 = ws[(3*8+nl)*97 + i*3 + k];
      #pragma unroll
      for (int t = 0; t < 8; ++t){
        float xv = xs[b*321 + (t+k)*32 + i];
        acc[0][t] += xv*w0; acc[1][t] += xv*w1; acc[2][t] += xv*w2; acc[3][t] += xv*w3;
      }
    }
  }
  #pragma unroll
  for (int ss = 0; ss < 4; ++ss){
    int n = n0 + nl;
    float s1 = 0.f, s2 = 0.f;
    #pragma unroll
    for (int t = 0; t < 8; ++t){
      float v = acc[ss][t];
      int s = (t0 + t)*4 + ss;
      hp[s*4096 + n*32 + b] = v;       // [s][n][b]
      s1 += v; s2 += v*v;
    }
    #pragma unroll
    for (int off = 1; off < 32; off <<= 1){
      s1 += __shfl_xor(s1, off);
      s2 += __shfl_xor(s2, off);
    }
    if (b == 0){
      int c = ss*128 + n;
      atomicAdd(&s1g[c], s1);
      atomicAdd(&s2g[c], s2);
    }
  }
}

// ---------------- K2: finalize BN1 -> a1[c], b1[c]
__global__ void k_bn1(const float* __restrict__ s1g, const float* __restrict__ s2g,
                      const float* __restrict__ g, const float* __restrict__ bb,
                      float* __restrict__ a1, float* __restrict__ b1){
  int c = threadIdx.x;  // 512
  float m = s1g[c] * (1.f/16384.f);
  float v = s2g[c] * (1.f/16384.f) - m*m;
  float sc = g[c] * rsqrtf(v + EPSV);
  a1[c] = sc;
  b1[c] = bb[c] - m*sc;
}

// ---------------- K3: fused BN1-apply + LIF1 + per-step BN2(batch) + LIF2 + TS-mean downsample
__global__ __launch_bounds__(256) void k_lif(const float* __restrict__ hp,
        const float* __restrict__ a1, const float* __restrict__ b1,
        const float* __restrict__ beta1, const float* __restrict__ g2v, const float* __restrict__ b2v,
        const float* __restrict__ beta2, float* __restrict__ md){
  const int tid = threadIdx.x;
  const int b = tid & 31;
  const int n = blockIdx.x * 8 + (tid >> 5);
  float a1r0 = a1[0*128+n], a1r1 = a1[1*128+n], a1r2 = a1[2*128+n], a1r3 = a1[3*128+n];
  float b1r0 = b1[0*128+n], b1r1 = b1[1*128+n], b1r2 = b1[2*128+n], b1r3 = b1[3*128+n];
  float be1 = fminf(fmaxf(beta1[n], 0.f), 0.99f);
  float be2 = fminf(fmaxf(beta2[n], 0.f), 0.99f);
  float g2 = g2v[n], bb2 = b2v[n];
  float m1 = 0.f, r1 = 0.f, m2 = 0.f, r2 = 0.f;
  const float* base = hp + n*32 + b;   // +s*4096
  float c0 = base[0], c1 = base[4096], c2 = base[2*4096], c3 = base[3*4096];

#define LIF_STEP(CV, A1R, B1R) { \
    float x1 = CV*A1R + B1R; \
    m1 = be1*m1 + x1 - r1; \
    bool sp = (m1 > 1.0f); \
    unsigned long long mk = __ballot(sp); \
    float spk = sp ? 1.f : 0.f; r1 = spk; \
    unsigned hf = (tid & 32) ? (unsigned)(mk >> 32) : (unsigned)mk; \
    float mean = (float)__popc(hf) * 0.03125f; \
    float var = mean - mean*mean; \
    float h2 = (spk - mean) * rsqrtf(var + EPSV) * g2 + bb2; \
    m2 = be2*m2 + h2 - r2; \
    r2 = (m2 > 1.0f) ? 1.f : 0.f; \
    accd += m2; }

  for (int t = 0; t < 512; ++t){
    float n0v = 0.f, n1v = 0.f, n2v = 0.f, n3v = 0.f;
    if (t < 511){
      const float* nb = base + (size_t)(t+1)*16384;
      n0v = nb[0]; n1v = nb[4096]; n2v = nb[2*4096]; n3v = nb[3*4096];
    }
    float accd = 0.f;
    LIF_STEP(c0, a1r0, b1r0)
    LIF_STEP(c1, a1r1, b1r1)
    LIF_STEP(c2, a1r2, b1r2)
    LIF_STEP(c3, a1r3, b1r3)
    md[(b*512 + t)*128 + n] = accd * 0.25f;
    c0 = n0v; c1 = n1v; c2 = n2v; c3 = n3v;
  }
#undef LIF_STEP
}

// ---------------- K4: gi = concat(x, mem_down) @ W_ih^T + b_ih   (M=16384, N=384, K=160)
__global__ __launch_bounds__(256) void k_gemm_gi(const float* __restrict__ x, const float* __restrict__ md,
        const float* __restrict__ wih, const float* __restrict__ bih, float* __restrict__ gi){
  __shared__ float As[16*68];
  __shared__ float Bs[16*68];
  const int tid = threadIdx.x;
  const int lk = tid & 15, lr = tid >> 4;
  const int tn = tid & 15, tm = tid >> 4;
  const int mb = blockIdx.x*64, nb = blockIdx.y*64;
  float acc[4][4] = {};
  for (int kc = 0; kc < 10; ++kc){
    int k0 = kc*16;
    #pragma unroll
    for (int p = 0; p < 4; ++p){
      int m = mb + lr + p*16;
      int k = k0 + lk;
      float v = (k < 32) ? x[m*32 + k] : md[m*128 + (k - 32)];
      As[lk*68 + lr + p*16] = v;
      int j = nb + lr + p*16;
      Bs[lk*68 + lr + p*16] = wih[j*160 + k];
    }
    __syncthreads();
    #pragma unroll
    for (int kk = 0; kk < 16; ++kk){
      float4 a4 = *(float4*)&As[kk*68 + tm*4];
      float4 b4 = *(float4*)&Bs[kk*68 + tn*4];
      float aa[4] = {a4.x, a4.y, a4.z, a4.w};
      float bb[4] = {b4.x, b4.y, b4.z, b4.w};
      #pragma unroll
      for (int i2 = 0; i2 < 4; ++i2)
        #pragma unroll
        for (int j2 = 0; j2 < 4; ++j2) acc[i2][j2] += aa[i2]*bb[j2];
    }
    __syncthreads();
  }
  float4 bi = *(const float4*)&bih[nb + tn*4];
  #pragma unroll
  for (int mi = 0; mi < 4; ++mi){
    int m = mb + tm*4 + mi;
    float4 o;
    o.x = acc[mi][0] + bi.x; o.y = acc[mi][1] + bi.y;
    o.z = acc[mi][2] + bi.z; o.w = acc[mi][3] + bi.w;
    *(float4*)&gi[m*384 + nb + tn*4] = o;
  }
}

// ---------------- K5: GRU recurrence v6.
// 32 blocks (1/batch), 512 threads. Thread (j = tid>>2, quarter = tid&3): 3 gate dots over
// a K-quarter. Quarter reduce via DPP quad_perm (VALU pipe, no LDS, no addr calc).
template<int SEL>
__device__ __forceinline__ float dpp_qp(float x){
  return __int_as_float(__builtin_amdgcn_mov_dpp(__float_as_int(x), SEL, 0xF, 0xF, true));
}
#define FMA4(W,H) (W.x*H.x + W.y*H.y + W.z*H.z + W.w*H.w)
__global__ __launch_bounds__(512, 2) void k_gru(const float* __restrict__ gi, const float* __restrict__ whh,
        const float* __restrict__ bhh, float* __restrict__ gout){
  const int b = blockIdx.x;
  const int tid = threadIdx.x;
  const int j = tid >> 2;
  const int quarter = tid & 3;
  __shared__ float hs[2][4][36];   // [buf][quarter][32+4 pad]
  const float* wbr = &whh[(size_t)(      j)*128 + quarter*32];
  const float* wbz = &whh[(size_t)(128 + j)*128 + quarter*32];
  const float* wbn = &whh[(size_t)(256 + j)*128 + quarter*32];
  float4 wr0 = *(const float4*)(wbr+ 0), wr1 = *(const float4*)(wbr+ 4),
         wr2 = *(const float4*)(wbr+ 8), wr3 = *(const float4*)(wbr+12),
         wr4 = *(const float4*)(wbr+16), wr5 = *(const float4*)(wbr+20),
         wr6 = *(const float4*)(wbr+24), wr7 = *(const float4*)(wbr+28);
  float4 wz0 = *(const float4*)(wbz+ 0), wz1 = *(const float4*)(wbz+ 4),
         wz2 = *(const float4*)(wbz+ 8), wz3 = *(const float4*)(wbz+12),
         wz4 = *(const float4*)(wbz+16), wz5 = *(const float4*)(wbz+20),
         wz6 = *(const float4*)(wbz+24), wz7 = *(const float4*)(wbz+28);
  float4 wn0 = *(const float4*)(wbn+ 0), wn1 = *(const float4*)(wbn+ 4),
         wn2 = *(const float4*)(wbn+ 8), wn3 = *(const float4*)(wbn+12),
         wn4 = *(const float4*)(wbn+16), wn5 = *(const float4*)(wbn+20),
         wn6 = *(const float4*)(wbn+24), wn7 = *(const float4*)(wbn+28);
  float bh_r = 0.f, bh_z = 0.f, bh_n = 0.f;
  float gir = 0.f, giz = 0.f, gin = 0.f;
  const float* gib = gi + (size_t)b*512*384;
  if (!quarter){
    bh_r = bhh[j]; bh_z = bhh[128+j]; bh_n = bhh[256+j];
    gir = gib[j]; giz = gib[128+j]; gin = gib[256+j];   // prefetch t=0
  }
  if (tid < 128) hs[0][tid >> 5][tid & 31] = 0.f;
  float hprev = 0.f;
  __syncthreads();
  for (int t = 0; t < 512; ++t){
    float ngir = 0.f, ngiz = 0.f, ngin = 0.f;
    if (!quarter && t < 511){
      const float* gp = gib + (size_t)(t+1)*384;
      ngir = gp[j]; ngiz = gp[128+j]; ngin = gp[256+j];
    }
    const float* hq = &hs[t & 1][quarter][0];
    float4 h0 = *(const float4*)(hq+ 0), h1 = *(const float4*)(hq+ 4),
           h2 = *(const float4*)(hq+ 8), h3 = *(const float4*)(hq+12),
           h4 = *(const float4*)(hq+16), h5 = *(const float4*)(hq+20),
           h6 = *(const float4*)(hq+24), h7 = *(const float4*)(hq+28);
    float ar = FMA4(wr0,h0) + FMA4(wr1,h1) + FMA4(wr2,h2) + FMA4(wr3,h3)
             + FMA4(wr4,h4) + FMA4(wr5,h5) + FMA4(wr6,h6) + FMA4(wr7,h7);
    float az = FMA4(wz0,h0) + FMA4(wz1,h1) + FMA4(wz2,h2) + FMA4(wz3,h3)
             + FMA4(wz4,h4) + FMA4(wz5,h5) + FMA4(wz6,h6) + FMA4(wz7,h7);
    float an = FMA4(wn0,h0) + FMA4(wn1,h1) + FMA4(wn2,h2) + FMA4(wn3,h3)
             + FMA4(wn4,h4) + FMA4(wn5,h5) + FMA4(wn6,h6) + FMA4(wn7,h7);
    // quad reduce: xor1 = quad_perm[1,0,3,2] (0xB1), xor2 = quad_perm[2,3,0,1] (0x4E)
    ar += dpp_qp<0xB1>(ar); ar += dpp_qp<0x4E>(ar);
    az += dpp_qp<0xB1>(az); az += dpp_qp<0x4E>(az);
    an += dpp_qp<0xB1>(an); an += dpp_qp<0x4E>(an);
    if (!quarter){
      float r = fsigmoid(gir + ar + bh_r);
      float z = fsigmoid(giz + az + bh_z);
      float nn = ftanh(gin + r*(an + bh_n));
      float hn = (1.f - z)*nn + z*hprev;
      hprev = hn;
      hs[(t + 1) & 1][j >> 5][j & 31] = hn;
      gout[((size_t)b*512 + t)*128 + j] = hn;
    }
    gir = ngir; giz = ngiz; gin = ngin;
    __syncthreads();
  }
}
#undef FMA4

// ---------------- K6: Q,K,V = g @ [qw;kw;vw]^T + bias. Q,K emitted as bf16; V as f32.
__global__ __launch_bounds__(256) void k_gemm_qkv(const float* __restrict__ g,
        const float* __restrict__ qw, const float* __restrict__ qb2,
        const float* __restrict__ kw, const float* __restrict__ kb2,
        const float* __restrict__ vw, const float* __restrict__ vb2,
        unsigned short* __restrict__ Qbf, unsigned short* __restrict__ Kbf, float* __restrict__ Vb){
  __shared__ float As[16*68];
  __shared__ float Bs[16*68];
  const int tid = threadIdx.x;
  const int lk = tid & 15, lr = tid >> 4;
  const int tn = tid & 15, tm = tid >> 4;
  const int mb = blockIdx.x*64, nb = blockIdx.y*64;
  float acc[4][4] = {};
  for (int kc = 0; kc < 8; ++kc){
    int k0 = kc*16;
    #pragma unroll
    for (int p = 0; p < 4; ++p){
      int m = mb + lr + p*16;
      As[lk*68 + lr + p*16] = g[m*128 + k0 + lk];
      int j = nb + lr + p*16;
      const float* wr = (j < 128) ? &qw[j*128] : (j < 256) ? &kw[(j-128)*128] : &vw[(j-256)*128];
      Bs[lk*68 + lr + p*16] = wr[k0 + lk];
    }
    __syncthreads();
    #pragma unroll
    for (int kk = 0; kk < 16; ++kk){
      float4 a4 = *(float4*)&As[kk*68 + tm*4];
      float4 b4 = *(float4*)&Bs[kk*68 + tn*4];
      float aa[4] = {a4.x, a4.y, a4.z, a4.w};
      float bb[4] = {b4.x, b4.y, b4.z, b4.w};
      #pragma unroll
      for (int i2 = 0; i2 < 4; ++i2)
        #pragma unroll
        for (int j2 = 0; j2 < 4; ++j2) acc[i2][j2] += aa[i2]*bb[j2];
    }
    __syncthreads();
  }
  int j0 = nb + tn*4;
  if (j0 < 256){
    // Q or K -> bf16
    unsigned short* dst = (j0 < 128) ? Qbf : Kbf;
    const float* bptr   = (j0 < 128) ? qb2 : kb2;
    int col = j0 & 127;
    float4 bi = *(const float4*)&bptr[col];
    #pragma unroll
    for (int mi = 0; mi < 4; ++mi){
      int m = mb + tm*4 + mi;
      ushort4 o;
      o.x = f2bf(acc[mi][0] + bi.x); o.y = f2bf(acc[mi][1] + bi.y);
      o.z = f2bf(acc[mi][2] + bi.z); o.w = f2bf(acc[mi][3] + bi.w);
      *(ushort4*)&dst[(size_t)m*128 + col] = o;
    }
  } else {
    int col = j0 - 256;
    float4 bi = *(const float4*)&vb2[col];
    #pragma unroll
    for (int mi = 0; mi < 4; ++mi){
      int m = mb + tm*4 + mi;
      float4 o;
      o.x = acc[mi][0] + bi.x; o.y = acc[mi][1] + bi.y;
      o.z = acc[mi][2] + bi.z; o.w = acc[mi][3] + bi.w;
      *(float4*)&Vb[(size_t)m*128 + col] = o;
    }
  }
}

// ---------------- K7: a[b][s] = mean_t sigmoid(scale * Q[b,t,:].K[b,s,:])  via bf16 MFMA
// grid (32 b, 8 s-tiles of 64); 4 waves, wave w owns s-rows w*16..w*16+15.
// A = K-tile (M=s), B = Q^T (N=t). C layout: col=lane&15 -> t, row=(lane>>4)*4+reg -> s.
__global__ __launch_bounds__(256) void k_attn(const unsigned short* __restrict__ Qbf,
        const unsigned short* __restrict__ Kbf, float* __restrict__ av){
  const int tid = threadIdx.x;
  const int b  = blockIdx.x;
  const int st = blockIdx.y;
  const int w  = tid >> 6;
  const int l  = tid & 63;
  const int c16 = l & 15;
  const int kg  = l >> 4;          // k-subgroup *8
  const float SC = 0.08838834764831845f; // 128^-0.5
  const unsigned short* kp = Kbf + ((size_t)(b*512 + st*64 + w*16 + c16))*128 + kg*8;
  bf16x8 a0 = *(const bf16x8*)(kp + 0);
  bf16x8 a1 = *(const bf16x8*)(kp + 32);
  bf16x8 a2 = *(const bf16x8*)(kp + 64);
  bf16x8 a3 = *(const bf16x8*)(kp + 96);
  const unsigned short* qb = Qbf + ((size_t)(b*512 + c16))*128 + kg*8;
  float ps0 = 0.f, ps1 = 0.f, ps2 = 0.f, ps3 = 0.f;
  for (int tt = 0; tt < 32; ++tt){
    const unsigned short* qp = qb + (size_t)tt*16*128;
    bf16x8 b0 = *(const bf16x8*)(qp + 0);
    bf16x8 b1 = *(const bf16x8*)(qp + 32);
    bf16x8 b2 = *(const bf16x8*)(qp + 64);
    bf16x8 b3 = *(const bf16x8*)(qp + 96);
    f32x4 acc = {0.f, 0.f, 0.f, 0.f};
    acc = __builtin_amdgcn_mfma_f32_16x16x32_bf16(a0, b0, acc, 0, 0, 0);
    acc = __builtin_amdgcn_mfma_f32_16x16x32_bf16(a1, b1, acc, 0, 0, 0);
    acc = __builtin_amdgcn_mfma_f32_16x16x32_bf16(a2, b2, acc, 0, 0, 0);
    acc = __builtin_amdgcn_mfma_f32_16x16x32_bf16(a3, b3, acc, 0, 0, 0);
    ps0 += fsigmoid(acc[0]*SC);
    ps1 += fsigmoid(acc[1]*SC);
    ps2 += fsigmoid(acc[2]*SC);
    ps3 += fsigmoid(acc[3]*SC);
  }
  // reduce over the 16 t-lanes (c16); kg group stays fixed
  #pragma unroll
  for (int off = 1; off < 16; off <<= 1){
    ps0 += __shfl_xor(ps0, off);
    ps1 += __shfl_xor(ps1, off);
    ps2 += __shfl_xor(ps2, off);
    ps3 += __shfl_xor(ps3, off);
  }
  if (c16 == 0){
    int sb = st*64 + w*16 + kg*4;
    av[b*512 + sb + 0] = ps0 * (1.f/512.f);
    av[b*512 + sb + 1] = ps1 * (1.f/512.f);
    av[b*512 + sb + 2] = ps2 * (1.f/512.f);
    av[b*512 + sb + 3] = ps3 * (1.f/512.f);
  }
}

// ---------------- K8: out0[b][c] = sum_s a[b][s] * V[b][s][c]
__global__ __launch_bounds__(128) void k_av(const float* __restrict__ av, const float* __restrict__ Vb,
        float* __restrict__ out0){
  int b = blockIdx.x, c = threadIdx.x;
  float acc = 0.f;
  for (int s = 0; s < 512; ++s) acc += av[b*512 + s] * Vb[(size_t)(b*512 + s)*128 + c];
  out0[b*128 + c] = acc;
}

// ---------------- K9: BN3(batch) + head
__global__ __launch_bounds__(256) void k_final(const float* __restrict__ out0,
        const float* __restrict__ g3, const float* __restrict__ b3,
        const float* __restrict__ hw, const float* __restrict__ hb, float* __restrict__ out){
  __shared__ float on[32*132];
  const int tid = threadIdx.x;
  if (tid < 128){
    int c = tid;
    float s = 0.f;
    for (int bq = 0; bq < 32; ++bq) s += out0[bq*128 + c];
    float m = s * (1.f/32.f);
    float v = 0.f;
    for (int bq = 0; bq < 32; ++bq){ float d = out0[bq*128 + c] - m; v += d*d; }
    v *= (1.f/32.f);
    float sc = g3[c] * rsqrtf(v + EPSV);
    float sh = b3[c] - m*sc;
    for (int bq = 0; bq < 32; ++bq) on[bq*132 + c] = out0[bq*128 + c]*sc + sh;
  }
  __syncthreads();
  for (int o = tid; o < 32*96; o += 256){
    int bq = o / 96, hh = o - bq*96;
    float acc = hb[hh];
    for (int k = 0; k < 128; ++k) acc += on[bq*132 + k] * hw[hh*128 + k];
    out[o] = acc;
  }
}

extern "C" void kernel_launch(void* const* d_in, const int* in_sizes, int n_in,
                              void* d_out, int out_size, void* d_ws, size_t ws_size,
                              hipStream_t stream){
  const float* x      = (const float*)d_in[0];
  const float* conv_w = (const float*)d_in[1];
  const float* conv_b = (const float*)d_in[2];
  const float* bn1_g  = (const float*)d_in[3];
  const float* bn1_b  = (const float*)d_in[4];
  const float* beta1  = (const float*)d_in[5];
  const float* bn2_g  = (const float*)d_in[6];
  const float* bn2_b  = (const float*)d_in[7];
  const float* beta2  = (const float*)d_in[8];
  const float* g_wih  = (const float*)d_in[9];
  const float* g_whh  = (const float*)d_in[10];
  const float* g_bih  = (const float*)d_in[11];
  const float* g_bhh  = (const float*)d_in[12];
  const float* q_w    = (const float*)d_in[13];
  const float* q_b    = (const float*)d_in[14];
  const float* k_w    = (const float*)d_in[15];
  const float* k_b    = (const float*)d_in[16];
  const float* v_w    = (const float*)d_in[17];
  const float* v_b    = (const float*)d_in[18];
  const float* bn3_g  = (const float*)d_in[19];
  const float* bn3_b  = (const float*)d_in[20];
  const float* head_w = (const float*)d_in[21];
  const float* head_b = (const float*)d_in[22];

  char* ws = (char*)d_ws;
  float* hp  = (float*)ws;                      // conv out, dead after k_lif
  float* md  = (float*)(ws + 33554432);
  float* g   = (float*)(ws + 41943040);
  float* s1g = (float*)(ws + 50331648);
  float* s2g = (float*)(ws + 50331648 + 2048);
  float* a1  = (float*)(ws + 50331648 + 4096);
  float* b1  = (float*)(ws + 50331648 + 6144);
  float* av  = (float*)(ws + 50331648 + 8192);
  float* out0= (float*)(ws + 50331648 + 8192 + 65536);
  float* gi  = (float*)ws;                      // reuse (h_perm dead after k_lif)
  unsigned short* Qbf = (unsigned short*)ws;            // 4 MB (gi dead after k_gru)
  unsigned short* Kbf = (unsigned short*)(ws + 4194304);// 4 MB
  float* Vb  = (float*)(ws + 16777216);                 // 8 MB f32

  (void)hipMemsetAsync(ws + 50331648, 0, 4096, stream);  // zero BN1 accumulators

  k_conv<<<dim3(64, 16), 256, 0, stream>>>(x, conv_w, conv_b, hp, s1g, s2g);
  k_bn1<<<1, 512, 0, stream>>>(s1g, s2g, bn1_g, bn1_b, a1, b1);
  k_lif<<<16, 256, 0, stream>>>(hp, a1, b1, beta1, bn2_g, bn2_b, beta2, md);
  k_gemm_gi<<<dim3(256, 6), 256, 0, stream>>>(x, md, g_wih, g_bih, gi);
  k_gru<<<32, 512, 0, stream>>>(gi, g_whh, g_bhh, g);
  k_gemm_qkv<<<dim3(256, 6), 256, 0, stream>>>(g, q_w, q_b, k_w, k_b, v_w, v_b, Qbf, Kbf, Vb);
  k_attn<<<dim3(32, 8), 256, 0, stream>>>(Qbf, Kbf, av);
  k_av<<<32, 128, 0, stream>>>(av, Vb, out0);
  k_final<<<1, 256, 0, stream>>>(out0, bn3_g, bn3_b, head_w, head_b, (float*)d_out);
}

// Round 8
// 710.540 us; speedup vs baseline: 1.4151x; 1.0134x over previous
//
#include <hip/hip_runtime.h>
#include <math.h>

#define EPSV 1e-5f

#if __has_builtin(__builtin_amdgcn_exp2f)
#define EXP2F(x) __builtin_amdgcn_exp2f(x)
#else
#define EXP2F(x) exp2f(x)
#endif
#if __has_builtin(__builtin_amdgcn_rcpf)
#define RCPF(x) __builtin_amdgcn_rcpf(x)
#else
#define RCPF(x) (1.0f/(x))
#endif

__device__ __forceinline__ float fsigmoid(float x){
  return RCPF(1.0f + EXP2F(-1.4426950408889634f * x));
}
__device__ __forceinline__ float ftanh(float x){
  return RCPF(0.5f + 0.5f * EXP2F(-2.8853900817779268f * x)) - 1.0f;
}
__device__ __forceinline__ unsigned short f2bf(float f){
  unsigned u = __float_as_uint(f);
  return (unsigned short)((u + 0x7FFFu + ((u >> 16) & 1u)) >> 16);
}

typedef __attribute__((ext_vector_type(8))) short bf16x8;
typedef __attribute__((ext_vector_type(4))) float f32x4;

// ---------------- K1: conv1d (pad=1,K=3) + bias -> h_perm [s][n][b], + BN1 stats, + x_bf emit
__global__ __launch_bounds__(256) void k_conv(const float* __restrict__ x, const float* __restrict__ w,
        const float* __restrict__ cb, float* __restrict__ hp, float* __restrict__ s1g, float* __restrict__ s2g,
        unsigned short* __restrict__ x_bf){
  __shared__ float xs[32*321];   // [b][tt(10)][i(32)]
  __shared__ float ws[32*97];
  __shared__ float bs[32];
  const int tid = threadIdx.x;
  const int t0 = blockIdx.x * 8;
  const int n0 = blockIdx.y * 8;
  for (int idx = tid; idx < 32*10*32; idx += 256){
    int bq = idx / 320; int rem = idx - bq*320; int tt = rem >> 5; int i = rem & 31;
    int tg = t0 - 1 + tt;
    float v = 0.f;
    if (tg >= 0 && tg < 512) v = x[(bq*512 + tg)*32 + i];
    xs[bq*321 + tt*32 + i] = v;
  }
  for (int idx = tid; idx < 32*96; idx += 256){
    int row = idx / 96; int within = idx - row*96;
    int ss = row >> 3; int nl = row & 7;
    int c = ss*128 + n0 + nl;
    ws[row*97 + within] = w[c*96 + within];
  }
  if (tid < 32){
    int ss = tid >> 3, nl = tid & 7;
    bs[tid] = cb[ss*128 + n0 + nl];
  }
  __syncthreads();
  if (blockIdx.y == 0){
    for (int idx = tid; idx < 32*8*32; idx += 256){
      int bq = idx >> 8; int rem = idx & 255; int tt = rem >> 5; int i = rem & 31;
      x_bf[(bq*512 + t0 + tt)*32 + i] = f2bf(xs[bq*321 + (tt+1)*32 + i]);
    }
  }
  const int b = tid & 31;
  const int nl = tid >> 5;
  float acc[4][8];
  #pragma unroll
  for (int ss = 0; ss < 4; ++ss){
    float bv = bs[ss*8 + nl];
    #pragma unroll
    for (int t = 0; t < 8; ++t) acc[ss][t] = bv;
  }
  for (int i = 0; i < 32; ++i){
    #pragma unroll
    for (int k = 0; k < 3; ++k){
      float w0 = ws[(0*8+nl)*97 + i*3 + k];
      float w1 = ws[(1*8+nl)*97 + i*3 + k];
      float w2 = ws[(2*8+nl)*97 + i*3 + k];
      float w3 = ws[(3*8+nl)*97 + i*3 + k];
      #pragma unroll
      for (int t = 0; t < 8; ++t){
        float xv = xs[b*321 + (t+k)*32 + i];
        acc[0][t] += xv*w0; acc[1][t] += xv*w1; acc[2][t] += xv*w2; acc[3][t] += xv*w3;
      }
    }
  }
  #pragma unroll
  for (int ss = 0; ss < 4; ++ss){
    int n = n0 + nl;
    float s1 = 0.f, s2 = 0.f;
    #pragma unroll
    for (int t = 0; t < 8; ++t){
      float v = acc[ss][t];
      int s = (t0 + t)*4 + ss;
      hp[s*4096 + n*32 + b] = v;
      s1 += v; s2 += v*v;
    }
    #pragma unroll
    for (int off = 1; off < 32; off <<= 1){
      s1 += __shfl_xor(s1, off);
      s2 += __shfl_xor(s2, off);
    }
    if (b == 0){
      int c = ss*128 + n;
      atomicAdd(&s1g[c], s1);
      atomicAdd(&s2g[c], s2);
    }
  }
}

// ---------------- K2: finalize BN1
__global__ void k_bn1(const float* __restrict__ s1g, const float* __restrict__ s2g,
                      const float* __restrict__ g, const float* __restrict__ bb,
                      float* __restrict__ a1, float* __restrict__ b1){
  int c = threadIdx.x;
  float m = s1g[c] * (1.f/16384.f);
  float v = s2g[c] * (1.f/16384.f) - m*m;
  float sc = g[c] * rsqrtf(v + EPSV);
  a1[c] = sc;
  b1[c] = bb[c] - m*sc;
}

// ---------------- K2b: weight converts (wih -> wih_bf, [qw;kw;vw] -> wqkv_bf)
__global__ __launch_bounds__(256) void k_cvt_all(const float* __restrict__ wih,
        const float* __restrict__ qw, const float* __restrict__ kw, const float* __restrict__ vw,
        unsigned short* __restrict__ wih_bf, unsigned short* __restrict__ wqkv_bf){
  int i = blockIdx.x*256 + threadIdx.x;
  if (i < 61440){ wih_bf[i] = f2bf(wih[i]); return; }
  int r = i - 61440;
  if (r < 16384){ wqkv_bf[r] = f2bf(qw[r]); return; }
  r -= 16384;
  if (r < 16384){ wqkv_bf[16384 + r] = f2bf(kw[r]); return; }
  r -= 16384;
  if (r < 16384){ wqkv_bf[32768 + r] = f2bf(vw[r]); }
}

// ---------------- K3: fused BN1-apply + LIF1 + BN2 + LIF2 + downsample -> md (bf16)
__global__ __launch_bounds__(256) void k_lif(const float* __restrict__ hp,
        const float* __restrict__ a1, const float* __restrict__ b1,
        const float* __restrict__ beta1, const float* __restrict__ g2v, const float* __restrict__ b2v,
        const float* __restrict__ beta2, unsigned short* __restrict__ md_bf){
  const int tid = threadIdx.x;
  const int b = tid & 31;
  const int n = blockIdx.x * 8 + (tid >> 5);
  float a1r0 = a1[0*128+n], a1r1 = a1[1*128+n], a1r2 = a1[2*128+n], a1r3 = a1[3*128+n];
  float b1r0 = b1[0*128+n], b1r1 = b1[1*128+n], b1r2 = b1[2*128+n], b1r3 = b1[3*128+n];
  float be1 = fminf(fmaxf(beta1[n], 0.f), 0.99f);
  float be2 = fminf(fmaxf(beta2[n], 0.f), 0.99f);
  float g2 = g2v[n], bb2 = b2v[n];
  float m1 = 0.f, r1 = 0.f, m2 = 0.f, r2 = 0.f;
  const float* base = hp + n*32 + b;
  float c0 = base[0], c1 = base[4096], c2 = base[2*4096], c3 = base[3*4096];

#define LIF_STEP(CV, A1R, B1R) { \
    float x1 = CV*A1R + B1R; \
    m1 = be1*m1 + x1 - r1; \
    bool sp = (m1 > 1.0f); \
    unsigned long long mk = __ballot(sp); \
    float spk = sp ? 1.f : 0.f; r1 = spk; \
    unsigned hf = (tid & 32) ? (unsigned)(mk >> 32) : (unsigned)mk; \
    float mean = (float)__popc(hf) * 0.03125f; \
    float var = mean - mean*mean; \
    float h2 = (spk - mean) * rsqrtf(var + EPSV) * g2 + bb2; \
    m2 = be2*m2 + h2 - r2; \
    r2 = (m2 > 1.0f) ? 1.f : 0.f; \
    accd += m2; }

  for (int t = 0; t < 512; ++t){
    float n0v = 0.f, n1v = 0.f, n2v = 0.f, n3v = 0.f;
    if (t < 511){
      const float* nb = base + (size_t)(t+1)*16384;
      n0v = nb[0]; n1v = nb[4096]; n2v = nb[2*4096]; n3v = nb[3*4096];
    }
    float accd = 0.f;
    LIF_STEP(c0, a1r0, b1r0)
    LIF_STEP(c1, a1r1, b1r1)
    LIF_STEP(c2, a1r2, b1r2)
    LIF_STEP(c3, a1r3, b1r3)
    md_bf[(b*512 + t)*128 + n] = f2bf(accd * 0.25f);
    c0 = n0v; c1 = n1v; c2 = n2v; c3 = n3v;
  }
#undef LIF_STEP
}

// ---------------- K4: gi = concat(x, md) @ W_ih^T + b_ih  via bf16 MFMA (K=160, 5 chunks)
// wave w -> m-tile (blockIdx.x*4+w)*16; loops 24 n-tiles. C: row=(l>>4)*4+reg, col=l&15.
__global__ __launch_bounds__(256) void k_mm_gi(const unsigned short* __restrict__ xbf,
        const unsigned short* __restrict__ mdbf, const unsigned short* __restrict__ wihbf,
        const float* __restrict__ bih, float* __restrict__ gi){
  const int tid = threadIdx.x;
  const int w = tid >> 6, l = tid & 63;
  const int c16 = l & 15, kg = l >> 4;
  const int m0 = (blockIdx.x*4 + w) * 16;
  const int mrow = m0 + c16;
  bf16x8 a0 = *(const bf16x8*)&xbf[(size_t)mrow*32 + kg*8];
  const unsigned short* mdp = &mdbf[(size_t)mrow*128 + kg*8];
  bf16x8 a1 = *(const bf16x8*)(mdp + 0);
  bf16x8 a2 = *(const bf16x8*)(mdp + 32);
  bf16x8 a3 = *(const bf16x8*)(mdp + 64);
  bf16x8 a4 = *(const bf16x8*)(mdp + 96);
  for (int nt = 0; nt < 24; ++nt){
    int n0 = nt*16;
    const unsigned short* wp = &wihbf[(size_t)(n0 + c16)*160 + kg*8];
    bf16x8 b0 = *(const bf16x8*)(wp + 0);
    bf16x8 b1 = *(const bf16x8*)(wp + 32);
    bf16x8 b2 = *(const bf16x8*)(wp + 64);
    bf16x8 b3 = *(const bf16x8*)(wp + 96);
    bf16x8 b4 = *(const bf16x8*)(wp + 128);
    f32x4 acc = {0.f,0.f,0.f,0.f};
    acc = __builtin_amdgcn_mfma_f32_16x16x32_bf16(a0, b0, acc, 0, 0, 0);
    acc = __builtin_amdgcn_mfma_f32_16x16x32_bf16(a1, b1, acc, 0, 0, 0);
    acc = __builtin_amdgcn_mfma_f32_16x16x32_bf16(a2, b2, acc, 0, 0, 0);
    acc = __builtin_amdgcn_mfma_f32_16x16x32_bf16(a3, b3, acc, 0, 0, 0);
    acc = __builtin_amdgcn_mfma_f32_16x16x32_bf16(a4, b4, acc, 0, 0, 0);
    float bias = bih[n0 + c16];
    #pragma unroll
    for (int r = 0; r < 4; ++r){
      gi[(size_t)(m0 + kg*4 + r)*384 + n0 + c16] = acc[r] + bias;
    }
  }
}

// ---------------- K5: GRU recurrence v7. Weights loaded via VOLATILE inline-asm global_load
// (cannot be rematerialized/sunk -> forced VGPR residency). DPP quad reduce. gout -> bf16.
template<int SEL>
__device__ __forceinline__ float dpp_qp(float x){
  return __int_as_float(__builtin_amdgcn_mov_dpp(__float_as_int(x), SEL, 0xF, 0xF, true));
}
#define FMA4(W,H) (W[0]*H[0] + W[1]*H[1] + W[2]*H[2] + W[3]*H[3])
#define GLD(dst, p, OFF) asm volatile("global_load_dwordx4 %0, %1, off offset:" OFF : "=v"(dst) : "v"(p))
__global__ __launch_bounds__(512, 2) void k_gru(const float* __restrict__ gi, const float* __restrict__ whh,
        const float* __restrict__ bhh, unsigned short* __restrict__ gout_bf){
  const int b = blockIdx.x;
  const int tid = threadIdx.x;
  const int j = tid >> 2;
  const int quarter = tid & 3;
  __shared__ float hs[2][4][36];
  const float* wbr = &whh[(size_t)(      j)*128 + quarter*32];
  const float* wbz = &whh[(size_t)(128 + j)*128 + quarter*32];
  const float* wbn = &whh[(size_t)(256 + j)*128 + quarter*32];
  f32x4 wr0, wr1, wr2, wr3, wr4, wr5, wr6, wr7;
  f32x4 wz0, wz1, wz2, wz3, wz4, wz5, wz6, wz7;
  f32x4 wn0, wn1, wn2, wn3, wn4, wn5, wn6, wn7;
  GLD(wr0, wbr, "0");  GLD(wr1, wbr, "16"); GLD(wr2, wbr, "32"); GLD(wr3, wbr, "48");
  GLD(wr4, wbr, "64"); GLD(wr5, wbr, "80"); GLD(wr6, wbr, "96"); GLD(wr7, wbr, "112");
  GLD(wz0, wbz, "0");  GLD(wz1, wbz, "16"); GLD(wz2, wbz, "32"); GLD(wz3, wbz, "48");
  GLD(wz4, wbz, "64"); GLD(wz5, wbz, "80"); GLD(wz6, wbz, "96"); GLD(wz7, wbz, "112");
  GLD(wn0, wbn, "0");  GLD(wn1, wbn, "16"); GLD(wn2, wbn, "32"); GLD(wn3, wbn, "48");
  GLD(wn4, wbn, "64"); GLD(wn5, wbn, "80"); GLD(wn6, wbn, "96"); GLD(wn7, wbn, "112");
  asm volatile("s_waitcnt vmcnt(0)" ::: "memory");
  __builtin_amdgcn_sched_barrier(0);
  float bh_r = 0.f, bh_z = 0.f, bh_n = 0.f;
  float gir = 0.f, giz = 0.f, gin = 0.f;
  const float* gib = gi + (size_t)b*512*384;
  if (!quarter){
    bh_r = bhh[j]; bh_z = bhh[128+j]; bh_n = bhh[256+j];
    gir = gib[j]; giz = gib[128+j]; gin = gib[256+j];
  }
  if (tid < 128) hs[0][tid >> 5][tid & 31] = 0.f;
  float hprev = 0.f;
  __syncthreads();
  for (int t = 0; t < 512; ++t){
    float ngir = 0.f, ngiz = 0.f, ngin = 0.f;
    if (!quarter && t < 511){
      const float* gp = gib + (size_t)(t+1)*384;
      ngir = gp[j]; ngiz = gp[128+j]; ngin = gp[256+j];
    }
    const float* hq = &hs[t & 1][quarter][0];
    f32x4 h0 = *(const f32x4*)(hq+ 0), h1 = *(const f32x4*)(hq+ 4),
          h2 = *(const f32x4*)(hq+ 8), h3 = *(const f32x4*)(hq+12),
          h4 = *(const f32x4*)(hq+16), h5 = *(const f32x4*)(hq+20),
          h6 = *(const f32x4*)(hq+24), h7 = *(const f32x4*)(hq+28);
    float ar = FMA4(wr0,h0) + FMA4(wr1,h1) + FMA4(wr2,h2) + FMA4(wr3,h3)
             + FMA4(wr4,h4) + FMA4(wr5,h5) + FMA4(wr6,h6) + FMA4(wr7,h7);
    float az = FMA4(wz0,h0) + FMA4(wz1,h1) + FMA4(wz2,h2) + FMA4(wz3,h3)
             + FMA4(wz4,h4) + FMA4(wz5,h5) + FMA4(wz6,h6) + FMA4(wz7,h7);
    float an = FMA4(wn0,h0) + FMA4(wn1,h1) + FMA4(wn2,h2) + FMA4(wn3,h3)
             + FMA4(wn4,h4) + FMA4(wn5,h5) + FMA4(wn6,h6) + FMA4(wn7,h7);
    ar += dpp_qp<0xB1>(ar); ar += dpp_qp<0x4E>(ar);
    az += dpp_qp<0xB1>(az); az += dpp_qp<0x4E>(az);
    an += dpp_qp<0xB1>(an); an += dpp_qp<0x4E>(an);
    if (!quarter){
      float r = fsigmoid(gir + ar + bh_r);
      float z = fsigmoid(giz + az + bh_z);
      float nn = ftanh(gin + r*(an + bh_n));
      float hn = (1.f - z)*nn + z*hprev;
      hprev = hn;
      hs[(t + 1) & 1][j >> 5][j & 31] = hn;
      gout_bf[((size_t)b*512 + t)*128 + j] = f2bf(hn);
    }
    gir = ngir; giz = ngiz; gin = ngin;
    __syncthreads();
  }
}
#undef FMA4
#undef GLD

// ---------------- K6: Q,K,V = g @ [qw;kw;vw]^T + bias via bf16 MFMA (K=128, 4 chunks)
__global__ __launch_bounds__(256) void k_mm_qkv(const unsigned short* __restrict__ gbf,
        const unsigned short* __restrict__ wbf, const float* __restrict__ qb2,
        const float* __restrict__ kb2, const float* __restrict__ vb2,
        unsigned short* __restrict__ Qbf, unsigned short* __restrict__ Kbf, float* __restrict__ Vb){
  const int tid = threadIdx.x;
  const int w = tid >> 6, l = tid & 63;
  const int c16 = l & 15, kg = l >> 4;
  const int m0 = (blockIdx.x*4 + w) * 16;
  const unsigned short* gp = &gbf[(size_t)(m0 + c16)*128 + kg*8];
  bf16x8 a0 = *(const bf16x8*)(gp + 0);
  bf16x8 a1 = *(const bf16x8*)(gp + 32);
  bf16x8 a2 = *(const bf16x8*)(gp + 64);
  bf16x8 a3 = *(const bf16x8*)(gp + 96);
  for (int nt = 0; nt < 24; ++nt){
    int n0 = nt*16;
    const unsigned short* wp = &wbf[(size_t)(n0 + c16)*128 + kg*8];
    bf16x8 b0 = *(const bf16x8*)(wp + 0);
    bf16x8 b1 = *(const bf16x8*)(wp + 32);
    bf16x8 b2 = *(const bf16x8*)(wp + 64);
    bf16x8 b3 = *(const bf16x8*)(wp + 96);
    f32x4 acc = {0.f,0.f,0.f,0.f};
    acc = __builtin_amdgcn_mfma_f32_16x16x32_bf16(a0, b0, acc, 0, 0, 0);
    acc = __builtin_amdgcn_mfma_f32_16x16x32_bf16(a1, b1, acc, 0, 0, 0);
    acc = __builtin_amdgcn_mfma_f32_16x16x32_bf16(a2, b2, acc, 0, 0, 0);
    acc = __builtin_amdgcn_mfma_f32_16x16x32_bf16(a3, b3, acc, 0, 0, 0);
    int n = n0 + c16;
    if (n < 128){
      float bias = qb2[n];
      #pragma unroll
      for (int r = 0; r < 4; ++r)
        Qbf[(size_t)(m0 + kg*4 + r)*128 + n] = f2bf(acc[r] + bias);
    } else if (n < 256){
      float bias = kb2[n-128];
      #pragma unroll
      for (int r = 0; r < 4; ++r)
        Kbf[(size_t)(m0 + kg*4 + r)*128 + (n-128)] = f2bf(acc[r] + bias);
    } else {
      float bias = vb2[n-256];
      #pragma unroll
      for (int r = 0; r < 4; ++r)
        Vb[(size_t)(m0 + kg*4 + r)*128 + (n-256)] = acc[r] + bias;
    }
  }
}

// ---------------- K7: a[b][s] = mean_t sigmoid(scale * Q.K) via bf16 MFMA
__global__ __launch_bounds__(256) void k_attn(const unsigned short* __restrict__ Qbf,
        const unsigned short* __restrict__ Kbf, float* __restrict__ av){
  const int tid = threadIdx.x;
  const int b  = blockIdx.x;
  const int st = blockIdx.y;
  const int w  = tid >> 6;
  const int l  = tid & 63;
  const int c16 = l & 15;
  const int kg  = l >> 4;
  const float SC = 0.08838834764831845f;
  const unsigned short* kp = Kbf + ((size_t)(b*512 + st*64 + w*16 + c16))*128 + kg*8;
  bf16x8 a0 = *(const bf16x8*)(kp + 0);
  bf16x8 a1 = *(const bf16x8*)(kp + 32);
  bf16x8 a2 = *(const bf16x8*)(kp + 64);
  bf16x8 a3 = *(const bf16x8*)(kp + 96);
  const unsigned short* qb = Qbf + ((size_t)(b*512 + c16))*128 + kg*8;
  float ps0 = 0.f, ps1 = 0.f, ps2 = 0.f, ps3 = 0.f;
  for (int tt = 0; tt < 32; ++tt){
    const unsigned short* qp = qb + (size_t)tt*16*128;
    bf16x8 b0 = *(const bf16x8*)(qp + 0);
    bf16x8 b1 = *(const bf16x8*)(qp + 32);
    bf16x8 b2 = *(const bf16x8*)(qp + 64);
    bf16x8 b3 = *(const bf16x8*)(qp + 96);
    f32x4 acc = {0.f, 0.f, 0.f, 0.f};
    acc = __builtin_amdgcn_mfma_f32_16x16x32_bf16(a0, b0, acc, 0, 0, 0);
    acc = __builtin_amdgcn_mfma_f32_16x16x32_bf16(a1, b1, acc, 0, 0, 0);
    acc = __builtin_amdgcn_mfma_f32_16x16x32_bf16(a2, b2, acc, 0, 0, 0);
    acc = __builtin_amdgcn_mfma_f32_16x16x32_bf16(a3, b3, acc, 0, 0, 0);
    ps0 += fsigmoid(acc[0]*SC);
    ps1 += fsigmoid(acc[1]*SC);
    ps2 += fsigmoid(acc[2]*SC);
    ps3 += fsigmoid(acc[3]*SC);
  }
  #pragma unroll
  for (int off = 1; off < 16; off <<= 1){
    ps0 += __shfl_xor(ps0, off);
    ps1 += __shfl_xor(ps1, off);
    ps2 += __shfl_xor(ps2, off);
    ps3 += __shfl_xor(ps3, off);
  }
  if (c16 == 0){
    int sb = st*64 + w*16 + kg*4;
    av[b*512 + sb + 0] = ps0 * (1.f/512.f);
    av[b*512 + sb + 1] = ps1 * (1.f/512.f);
    av[b*512 + sb + 2] = ps2 * (1.f/512.f);
    av[b*512 + sb + 3] = ps3 * (1.f/512.f);
  }
}

// ---------------- K8: out0[b][c] = sum_s a[b][s] * V[b][s][c]
__global__ __launch_bounds__(128) void k_av(const float* __restrict__ av, const float* __restrict__ Vb,
        float* __restrict__ out0){
  int b = blockIdx.x, c = threadIdx.x;
  float acc = 0.f;
  for (int s = 0; s < 512; ++s) acc += av[b*512 + s] * Vb[(size_t)(b*512 + s)*128 + c];
  out0[b*128 + c] = acc;
}

// ---------------- K9: BN3(batch) + head
__global__ __launch_bounds__(256) void k_final(const float* __restrict__ out0,
        const float* __restrict__ g3, const float* __restrict__ b3,
        const float* __restrict__ hw, const float* __restrict__ hb, float* __restrict__ out){
  __shared__ float on[32*132];
  const int tid = threadIdx.x;
  if (tid < 128){
    int c = tid;
    float s = 0.f;
    for (int bq = 0; bq < 32; ++bq) s += out0[bq*128 + c];
    float m = s * (1.f/32.f);
    float v = 0.f;
    for (int bq = 0; bq < 32; ++bq){ float d = out0[bq*128 + c] - m; v += d*d; }
    v *= (1.f/32.f);
    float sc = g3[c] * rsqrtf(v + EPSV);
    float sh = b3[c] - m*sc;
    for (int bq = 0; bq < 32; ++bq) on[bq*132 + c] = out0[bq*128 + c]*sc + sh;
  }
  __syncthreads();
  for (int o = tid; o < 32*96; o += 256){
    int bq = o / 96, hh = o - bq*96;
    float acc = hb[hh];
    for (int k = 0; k < 128; ++k) acc += on[bq*132 + k] * hw[hh*128 + k];
    out[o] = acc;
  }
}

extern "C" void kernel_launch(void* const* d_in, const int* in_sizes, int n_in,
                              void* d_out, int out_size, void* d_ws, size_t ws_size,
                              hipStream_t stream){
  const float* x      = (const float*)d_in[0];
  const float* conv_w = (const float*)d_in[1];
  const float* conv_b = (const float*)d_in[2];
  const float* bn1_g  = (const float*)d_in[3];
  const float* bn1_b  = (const float*)d_in[4];
  const float* beta1  = (const float*)d_in[5];
  const float* bn2_g  = (const float*)d_in[6];
  const float* bn2_b  = (const float*)d_in[7];
  const float* beta2  = (const float*)d_in[8];
  const float* g_wih  = (const float*)d_in[9];
  const float* g_whh  = (const float*)d_in[10];
  const float* g_bih  = (const float*)d_in[11];
  const float* g_bhh  = (const float*)d_in[12];
  const float* q_w    = (const float*)d_in[13];
  const float* q_b    = (const float*)d_in[14];
  const float* k_w    = (const float*)d_in[15];
  const float* k_b    = (const float*)d_in[16];
  const float* v_w    = (const float*)d_in[17];
  const float* v_b    = (const float*)d_in[18];
  const float* bn3_g  = (const float*)d_in[19];
  const float* bn3_b  = (const float*)d_in[20];
  const float* head_w = (const float*)d_in[21];
  const float* head_b = (const float*)d_in[22];

  char* ws = (char*)d_ws;
  // phase 1: hp [0,33.5MB) | md_bf @33554432 (4MB) | g_bf @37748736 (4MB) | x_bf @41943040 (1MB)
  //          wih_bf @42991616 | wqkv_bf @43114496 | stats @50331648 | av | out0
  // phase 2: gi reuses [0,25.2MB) after hp dead
  // phase 3: Qbf @0 (4MB), Kbf @4MB, Vb @8MB (f32 8MB) after gi dead
  float* hp            = (float*)ws;
  unsigned short* md_bf= (unsigned short*)(ws + 33554432);
  unsigned short* g_bf = (unsigned short*)(ws + 37748736);
  unsigned short* x_bf = (unsigned short*)(ws + 41943040);
  unsigned short* wih_bf  = (unsigned short*)(ws + 42991616);
  unsigned short* wqkv_bf = (unsigned short*)(ws + 43114496);
  float* s1g = (float*)(ws + 50331648);
  float* a1  = (float*)(ws + 50331648 + 4096);
  float* b1  = (float*)(ws + 50331648 + 6144);
  float* av  = (float*)(ws + 50331648 + 8192);
  float* out0= (float*)(ws + 50331648 + 8192 + 65536);
  float* gi  = (float*)ws;
  unsigned short* Qbf = (unsigned short*)ws;
  unsigned short* Kbf = (unsigned short*)(ws + 4194304);
  float* Vb  = (float*)(ws + 8388608);
  float* s2g = (float*)(ws + 50331648 + 2048);

  (void)hipMemsetAsync(ws + 50331648, 0, 4096, stream);

  k_conv<<<dim3(64, 16), 256, 0, stream>>>(x, conv_w, conv_b, hp, s1g, s2g, x_bf);
  k_bn1<<<1, 512, 0, stream>>>(s1g, s2g, bn1_g, bn1_b, a1, b1);
  k_cvt_all<<<432, 256, 0, stream>>>(g_wih, q_w, k_w, v_w, wih_bf, wqkv_bf);
  k_lif<<<16, 256, 0, stream>>>(hp, a1, b1, beta1, bn2_g, bn2_b, beta2, md_bf);
  k_mm_gi<<<256, 256, 0, stream>>>(x_bf, md_bf, wih_bf, g_bih, gi);
  k_gru<<<32, 512, 0, stream>>>(gi, g_whh, g_bhh, g_bf);
  k_mm_qkv<<<256, 256, 0, stream>>>(g_bf, wqkv_bf, q_b, k_b, v_b, Qbf, Kbf, Vb);
  k_attn<<<dim3(32, 8), 256, 0, stream>>>(Qbf, Kbf, av);
  k_av<<<32, 128, 0, stream>>>(av, Vb, out0);
  k_final<<<1, 256, 0, stream>>>(out0, bn3_g, bn3_b, head_w, head_b, (float*)d_out);
}